// Round 1
// baseline (2346.980 us; speedup 1.0000x reference)
//
#include <hip/hip_runtime.h>
#include <hip/hip_bf16.h>
#include <cstdint>
#include <cstddef>

#define NB 65536
#define DD 512
#define HH 1024

typedef __attribute__((ext_vector_type(8))) short short8;
typedef __attribute__((ext_vector_type(4))) short short4v;
typedef __attribute__((ext_vector_type(4))) float f32x4;

__device__ __forceinline__ float bf2f(short s){
  union { float f; unsigned u; } v; v.u = ((unsigned)(unsigned short)s) << 16; return v.f;
}
__device__ __forceinline__ short f2bf(float f){
  union { float f; unsigned u; } v; v.f = f;
  unsigned u = v.u;
  u += 0x7FFFu + ((u >> 16) & 1u);
  return (short)(u >> 16);
}
__device__ __forceinline__ float sigm(float x){ return 1.0f / (1.0f + __expf(-x)); }

// ---- stage a 128x32 bf16 tile (rows row0..+128, cols k0..+32 of a row-major
// [rows][ldk] matrix) into linear LDS [128][32] via global_load_lds width 16.
__device__ __forceinline__ void stage128x32(const short* __restrict__ g, int row0, int ldk, int k0,
                                            short* lds_base, int wave, int lane){
#pragma unroll
  for (int i = 0; i < 2; ++i){
    int c = wave*2 + i;   // chunk 0..7, each = 16 rows = 1024B
    const short* src = g + (size_t)(row0 + c*16 + (lane>>2)) * (size_t)ldk
                         + (size_t)(k0 + (lane&3)*8);
    __builtin_amdgcn_global_load_lds((const __attribute__((address_space(1))) void*)src,
                                     (__attribute__((address_space(3))) void*)(lds_base + c*512),
                                     16, 0, 0);
  }
}

// ---- 128x128 tile NT GEMM core: C[m,n] = sum_k A[m,k]*W[n,k], A:MxK, W:NxK (both bf16 row-major)
template<int K>
__device__ __forceinline__ void gemm_loop(const short* __restrict__ A, const short* __restrict__ W,
        int m0, int n0, short* smem, f32x4 acc[4][4], int wave, int lane)
{
  short* sA = smem;          // [128][32]
  short* sW = smem + 4096;   // [128][32]
  const int wm = (wave>>1)*64, wn = (wave&1)*64;
  const int lr = lane & 15, lk = (lane>>4)*8;
  for (int k0 = 0; k0 < K; k0 += 32){
    __syncthreads();                       // previous iter's ds_reads done
    stage128x32(A, m0, K, k0, sA, wave, lane);
    stage128x32(W, n0, K, k0, sW, wave, lane);
    __syncthreads();                       // staging drained (vmcnt0 before barrier)
    short8 af[4], bf[4];
#pragma unroll
    for (int i=0;i<4;++i) af[i] = *(const short8*)&sA[(wm + i*16 + lr)*32 + lk];
#pragma unroll
    for (int i=0;i<4;++i) bf[i] = *(const short8*)&sW[(wn + i*16 + lr)*32 + lk];
#pragma unroll
    for (int mi=0;mi<4;++mi)
#pragma unroll
      for (int ni=0;ni<4;++ni)
        acc[mi][ni] = __builtin_amdgcn_mfma_f32_16x16x32_bf16(af[mi], bf[ni], acc[mi][ni], 0, 0, 0);
  }
}

#define ZERO_ACC(acc) \
  _Pragma("unroll") for (int zi=0;zi<4;++zi) _Pragma("unroll") for (int zj=0;zj<4;++zj) \
    acc[zi][zj] = (f32x4){0.f,0.f,0.f,0.f};

// ---- CMS level GEMM1: H = relu(out @ w1^T + b1), bf16 out
__global__ __launch_bounds__(256) void k_gemm_h(const int* __restrict__ gs, int freq,
     const short* __restrict__ A, const short* __restrict__ W1, const float* __restrict__ b1,
     short* __restrict__ Hout)
{
  if (gs[0] % freq) return;
  __shared__ __align__(16) short smem[8192];
  const int tid = threadIdx.x, wave = tid>>6, lane = tid&63;
  const int m0 = blockIdx.x*128, n0 = blockIdx.y*128;
  f32x4 acc[4][4]; ZERO_ACC(acc);
  gemm_loop<DD>(A, W1, m0, n0, smem, acc, wave, lane);
  const int wm=(wave>>1)*64, wn=(wave&1)*64;
  const int rbase = m0 + wm + ((lane>>4)<<2);
  const int cbase = n0 + wn + (lane&15);
#pragma unroll
  for (int ni=0;ni<4;++ni){
    const float bias = b1[cbase + ni*16];
#pragma unroll
    for (int mi=0;mi<4;++mi)
#pragma unroll
      for (int r=0;r<4;++r){
        float v = acc[mi][ni][r] + bias;
        v = v > 0.f ? v : 0.f;
        Hout[(size_t)(rbase + mi*16 + r)*HH + (cbase + ni*16)] = f2bf(v);
      }
  }
}

// ---- CMS level GEMM2: out += H @ w2^T + b2 (fp32 master + bf16 shadow)
__global__ __launch_bounds__(256) void k_gemm_res(const int* __restrict__ gs, int freq,
     const short* __restrict__ Hb, const short* __restrict__ W2, const float* __restrict__ b2,
     float* __restrict__ outf, short* __restrict__ outb)
{
  if (gs[0] % freq) return;
  __shared__ __align__(16) short smem[8192];
  const int tid = threadIdx.x, wave = tid>>6, lane = tid&63;
  const int m0 = blockIdx.x*128, n0 = blockIdx.y*128;
  f32x4 acc[4][4]; ZERO_ACC(acc);
  gemm_loop<HH>(Hb, W2, m0, n0, smem, acc, wave, lane);
  const int wm=(wave>>1)*64, wn=(wave&1)*64;
  const int rbase = m0 + wm + ((lane>>4)<<2);
  const int cbase = n0 + wn + (lane&15);
#pragma unroll
  for (int ni=0;ni<4;++ni){
    const float bias = b2[cbase + ni*16];
#pragma unroll
    for (int mi=0;mi<4;++mi)
#pragma unroll
      for (int r=0;r<4;++r){
        size_t off = (size_t)(rbase + mi*16 + r)*DD + (cbase + ni*16);
        float v = acc[mi][ni][r] + bias + outf[off];
        outf[off] = v;
        outb[off] = f2bf(v);
      }
  }
}

// ---- gates: gsum = sum_j sigmoid(x_cms @ gw_j^T + gb_j), bf16 out
__global__ __launch_bounds__(256) void k_gates(const short* __restrict__ A, const short* __restrict__ WG,
     const float* __restrict__ bm, const float* __restrict__ bs, const float* __restrict__ bg,
     short* __restrict__ GS)
{
  __shared__ __align__(16) short smem[8192];
  const int tid = threadIdx.x, wave = tid>>6, lane = tid&63;
  const int m0 = blockIdx.x*128, n0 = blockIdx.y*128;
  const int wm=(wave>>1)*64, wn=(wave&1)*64;
  const int rbase = m0 + wm + ((lane>>4)<<2);
  const int cbase = n0 + wn + (lane&15);
  f32x4 sum[4][4]; ZERO_ACC(sum);
  for (int j=0;j<3;++j){
    f32x4 acc[4][4]; ZERO_ACC(acc);
    gemm_loop<DD>(A, WG + (size_t)j*HH*DD, m0, n0, smem, acc, wave, lane);
    const float* bj = (j==0) ? bm : ((j==1) ? bs : bg);
#pragma unroll
    for (int ni=0;ni<4;++ni){
      const float bias = bj[cbase + ni*16];
#pragma unroll
      for (int mi=0;mi<4;++mi)
#pragma unroll
        for (int r=0;r<4;++r)
          sum[mi][ni][r] += sigm(acc[mi][ni][r] + bias);
    }
  }
#pragma unroll
  for (int ni=0;ni<4;++ni)
#pragma unroll
    for (int mi=0;mi<4;++mi)
#pragma unroll
      for (int r=0;r<4;++r)
        GS[(size_t)(rbase + mi*16 + r)*HH + (cbase + ni*16)] = f2bf(sum[mi][ni][r]);
}

// ---- slow/fast fused GEMM (shared A, two W), also per-column sum of fast^2
__global__ __launch_bounds__(256) void k_slowfast(const short* __restrict__ A,
     const short* __restrict__ WS, const short* __restrict__ WF,
     short* __restrict__ SB, short* __restrict__ FB, float* __restrict__ f2sum)
{
  __shared__ __align__(16) short smem[12288];
  __shared__ float f2red[128];
  const int tid = threadIdx.x, wave = tid>>6, lane = tid&63;
  const int m0 = blockIdx.x*128, n0 = blockIdx.y*128;
  const int wm=(wave>>1)*64, wn=(wave&1)*64;
  const int lr = lane & 15, lk = (lane>>4)*8;
  f32x4 accS[4][4]; ZERO_ACC(accS);
  f32x4 accF[4][4]; ZERO_ACC(accF);
  for (int k0 = 0; k0 < DD; k0 += 32){
    __syncthreads();
    stage128x32(A,  m0, DD, k0, smem,        wave, lane);
    stage128x32(WS, n0, DD, k0, smem + 4096, wave, lane);
    stage128x32(WF, n0, DD, k0, smem + 8192, wave, lane);
    __syncthreads();
    short8 af[4], bsf[4], bff[4];
#pragma unroll
    for (int i=0;i<4;++i) af[i]  = *(const short8*)&smem[(wm + i*16 + lr)*32 + lk];
#pragma unroll
    for (int i=0;i<4;++i) bsf[i] = *(const short8*)&smem[4096 + (wn + i*16 + lr)*32 + lk];
#pragma unroll
    for (int i=0;i<4;++i) bff[i] = *(const short8*)&smem[8192 + (wn + i*16 + lr)*32 + lk];
#pragma unroll
    for (int mi=0;mi<4;++mi)
#pragma unroll
      for (int ni=0;ni<4;++ni){
        accS[mi][ni] = __builtin_amdgcn_mfma_f32_16x16x32_bf16(af[mi], bsf[ni], accS[mi][ni], 0,0,0);
        accF[mi][ni] = __builtin_amdgcn_mfma_f32_16x16x32_bf16(af[mi], bff[ni], accF[mi][ni], 0,0,0);
      }
  }
  for (int i=tid;i<128;i+=256) f2red[i]=0.f;
  __syncthreads();
  const int rbase = m0 + wm + ((lane>>4)<<2);
  const int ccol0 = wn + (lane&15);
#pragma unroll
  for (int ni=0;ni<4;++ni){
    const int ccol = ccol0 + ni*16;
    float p = 0.f;
#pragma unroll
    for (int mi=0;mi<4;++mi)
#pragma unroll
      for (int r=0;r<4;++r){
        float sv = accS[mi][ni][r], fv = accF[mi][ni][r];
        size_t off = (size_t)(rbase + mi*16 + r)*DD + (n0 + ccol);
        SB[off] = f2bf(sv);
        FB[off] = f2bf(fv);
        p += fv*fv;
      }
    atomicAdd(&f2red[ccol], p);
  }
  __syncthreads();
  if (tid < 128) atomicAdd(&f2sum[n0 + tid], f2red[tid]);
}

// ---- hebb = fast^T @ x_cms (TN GEMM via LDS transpose, split-K over B, atomic accum)
__global__ __launch_bounds__(256) void k_hebb(const short* __restrict__ FB,
     const short* __restrict__ XB, float* __restrict__ hebb)
{
  __shared__ __align__(16) short sT[10240];  // AsT[128][40] + BsT[128][40]
  const int tid = threadIdx.x, wave = tid>>6, lane = tid&63;
  const int o0 = blockIdx.x*128, d0 = blockIdx.y*128;
  const int bz = blockIdx.z;
  const int tr = tid>>3;          // 0..31 (b row in tile)
  const int tc = (tid&7)*16;      // col base
  const int wm=(wave>>1)*64, wn=(wave&1)*64;
  const int lr = lane & 15, lk = (lane>>4)*8;
  f32x4 acc[4][4]; ZERO_ACC(acc);
  for (int bb=0; bb<1024; bb+=32){
    const int b0 = bz*1024 + bb;
    __syncthreads();
#pragma unroll
    for (int h=0; h<2; ++h){
      short8 v = *(const short8*)&FB[(size_t)(b0+tr)*DD + o0 + tc + h*8];
#pragma unroll
      for (int j=0;j<8;++j) sT[(tc+h*8+j)*40 + tr] = v[j];
      short8 u = *(const short8*)&XB[(size_t)(b0+tr)*DD + d0 + tc + h*8];
#pragma unroll
      for (int j=0;j<8;++j) sT[5120 + (tc+h*8+j)*40 + tr] = u[j];
    }
    __syncthreads();
    short8 af[4], bf[4];
#pragma unroll
    for (int i=0;i<4;++i) af[i] = *(const short8*)&sT[(wm + i*16 + lr)*40 + lk];
#pragma unroll
    for (int i=0;i<4;++i) bf[i] = *(const short8*)&sT[5120 + (wn + i*16 + lr)*40 + lk];
#pragma unroll
    for (int mi=0;mi<4;++mi)
#pragma unroll
      for (int ni=0;ni<4;++ni)
        acc[mi][ni] = __builtin_amdgcn_mfma_f32_16x16x32_bf16(af[mi], bf[ni], acc[mi][ni], 0,0,0);
  }
  const int rbase = o0 + wm + ((lane>>4)<<2);
  const int cbase = d0 + wn + (lane&15);
#pragma unroll
  for (int mi=0;mi<4;++mi)
#pragma unroll
    for (int ni=0;ni<4;++ni)
#pragma unroll
      for (int r=0;r<4;++r)
        atomicAdd(&hebb[(size_t)(rbase + mi*16 + r)*DD + (cbase + ni*16)], acc[mi][ni][r]);
}

// ---- gate-out: gates = sigmoid(gsum @ g_out_w^T + g_out_b); per-block stat partials
__global__ __launch_bounds__(256) void k_gateout(const short* __restrict__ GS,
     const float* __restrict__ gow, const float* __restrict__ gob,
     float* __restrict__ metab, float* __restrict__ sens, float* __restrict__ gate,
     float* __restrict__ part)
{
  __shared__ float wsh[3072];
  __shared__ float red[12];
  const int tid = threadIdx.x, wave = tid>>6, lane = tid&63;
  for (int i=tid;i<3072;i+=256) wsh[i] = gow[i];
  __syncthreads();
  const int row = blockIdx.x*4 + wave;
  const int c0 = lane*16;
  short8 a = *(const short8*)&GS[(size_t)row*HH + c0];
  short8 b = *(const short8*)&GS[(size_t)row*HH + c0 + 8];
  float p0=0.f, p1=0.f, p2=0.f;
#pragma unroll
  for (int j=0;j<8;++j){ float v=bf2f(a[j]); int c=c0+j;   p0+=v*wsh[c]; p1+=v*wsh[1024+c]; p2+=v*wsh[2048+c]; }
#pragma unroll
  for (int j=0;j<8;++j){ float v=bf2f(b[j]); int c=c0+8+j; p0+=v*wsh[c]; p1+=v*wsh[1024+c]; p2+=v*wsh[2048+c]; }
  for (int off=32; off; off>>=1){
    p0 += __shfl_down(p0, off);
    p1 += __shfl_down(p1, off);
    p2 += __shfl_down(p2, off);
  }
  if (lane == 0){
    float m = sigm(p0 + gob[0]);
    float s = sigm(p1 + gob[1]);
    float g = sigm(p2 + gob[2]);
    metab[row]=m; sens[row]=s; gate[row]=g;
    red[wave*3+0]=m; red[wave*3+1]=s; red[wave*3+2]=g;
  }
  __syncthreads();
  if (tid < 3)
    part[(size_t)blockIdx.x*3 + tid] = red[tid] + red[3+tid] + red[6+tid] + red[9+tid];
}

__global__ __launch_bounds__(256) void k_statreduce(const float* __restrict__ part, float* __restrict__ sacc)
{
  __shared__ float sh[3][256];
  const int tid = threadIdx.x;
  float s0=0.f, s1=0.f, s2=0.f;
  for (int i=tid; i<16384; i+=256){ s0+=part[i*3]; s1+=part[i*3+1]; s2+=part[i*3+2]; }
  sh[0][tid]=s0; sh[1][tid]=s1; sh[2][tid]=s2;
  __syncthreads();
  if (tid < 3){
    float t=0.f;
    for (int i=0;i<256;++i) t += sh[tid][i];
    sacc[tid]=t;
  }
}

// ---- combined/SiLU-beta/LayerNorm epilogue: one wave per row
__global__ __launch_bounds__(256) void k_ln(const short* __restrict__ SB, const short* __restrict__ FB,
     const float* __restrict__ gate, const float* __restrict__ sens,
     const float* __restrict__ gam, const float* __restrict__ bet, float* __restrict__ out)
{
  const int tid = threadIdx.x, wave = tid>>6, lane = tid&63;
  const int row = blockIdx.x*4 + wave;
  const float g = gate[row], s = sens[row];
  const float bcoef = 0.5f + 2.0f*s;
  const int c0 = lane*8;
  short8 sv = *(const short8*)&SB[(size_t)row*DD + c0];
  short8 fv = *(const short8*)&FB[(size_t)row*DD + c0];
  float a[8]; float sum = 0.f;
#pragma unroll
  for (int j=0;j<8;++j){
    float c = bf2f(sv[j]) + bf2f(fv[j])*g;
    float av = c * sigm(bcoef*c);
    a[j] = av; sum += av;
  }
  for (int off=32; off; off>>=1) sum += __shfl_down(sum, off);
  sum = __shfl(sum, 0);
  const float mu = sum * (1.f/512.f);
  float vs = 0.f;
#pragma unroll
  for (int j=0;j<8;++j){ float d=a[j]-mu; vs += d*d; }
  for (int off=32; off; off>>=1) vs += __shfl_down(vs, off);
  vs = __shfl(vs, 0);
  const float rstd = rsqrtf(vs*(1.f/512.f) + 1e-5f);
  f32x4 o0, o1;
#pragma unroll
  for (int j=0;j<4;++j) o0[j] = (a[j]-mu)*rstd*gam[c0+j] + bet[c0+j];
#pragma unroll
  for (int j=0;j<4;++j) o1[j] = (a[4+j]-mu)*rstd*gam[c0+4+j] + bet[c0+4+j];
  *(f32x4*)&out[(size_t)row*DD + c0]     = o0;
  *(f32x4*)&out[(size_t)row*DD + c0 + 4] = o1;
}

// ---- new_W_fast + stats
__global__ __launch_bounds__(256) void k_wfast(const float* __restrict__ hebb,
     const float* __restrict__ f2sum, const float* __restrict__ sacc,
     const float* __restrict__ Wf, float* __restrict__ outw, float* __restrict__ outstats)
{
  const int idx = blockIdx.x*256 + threadIdx.x;
  if (idx >= 262144) return;
  const float inv = 1.f/65536.f;
  const float rate = sacc[0] * inv * 0.1f;
  const int o = idx >> 9;
  float w = Wf[idx];
  float h = hebb[idx] * inv;
  float forget = f2sum[o] * inv * w;
  outw[idx] = w + tanhf(h - forget) * rate;
  if (idx < 3) outstats[idx] = sacc[idx] * inv;
}

// ---- casts
__global__ __launch_bounds__(256) void k_castw(const float* __restrict__ src, short* __restrict__ dst, int n)
{
  int i = blockIdx.x*256 + threadIdx.x;
  if (i < n) dst[i] = f2bf(src[i]);
}
__global__ __launch_bounds__(256) void k_castx(const float* __restrict__ x,
     float* __restrict__ outf, short* __restrict__ outb)
{
  int i = blockIdx.x*256 + threadIdx.x;   // one float4 each; grid covers exactly
  f32x4 v = *(const f32x4*)&x[(size_t)i*4];
  *(f32x4*)&outf[(size_t)i*4] = v;
  short4v b;
#pragma unroll
  for (int j=0;j<4;++j) b[j] = f2bf(v[j]);
  *(short4v*)&outb[(size_t)i*4] = b;
}

extern "C" void kernel_launch(void* const* d_in, const int* in_sizes, int n_in,
                              void* d_out, int out_size, void* d_ws, size_t ws_size,
                              hipStream_t stream)
{
  const float* x    = (const float*)d_in[0];
  const int*   gs   = (const int*)d_in[1];
  const float* w1   = (const float*)d_in[2];
  const float* b1   = (const float*)d_in[3];
  const float* w2   = (const float*)d_in[4];
  const float* b2   = (const float*)d_in[5];
  const float* gmw  = (const float*)d_in[6];
  const float* gmb  = (const float*)d_in[7];
  const float* gsw  = (const float*)d_in[8];
  const float* gsb  = (const float*)d_in[9];
  const float* ggw  = (const float*)d_in[10];
  const float* ggb  = (const float*)d_in[11];
  const float* gow  = (const float*)d_in[12];
  const float* gob  = (const float*)d_in[13];
  const float* wslow= (const float*)d_in[14];
  const float* wfast= (const float*)d_in[15];
  const float* gam  = (const float*)d_in[16];
  const float* bet  = (const float*)d_in[17];

  char* ws = (char*)d_ws;
  float* outf  = (float*)(ws + 0);            // 134217728 B (dead after CMS -> reused below)
  short* outb  = (short*)(ws + 134217728);    // 67108864 B (x_cms bf16)
  short* hbuf  = (short*)(ws + 201326592);    // 134217728 B (h bf16, reused as gsum)
  short* wcW1  = (short*)(ws + 335544320);    // 3145728
  short* wcW2  = (short*)(ws + 338690048);    // 3145728
  short* wcG   = (short*)(ws + 341835776);    // 3145728
  short* wcWS  = (short*)(ws + 344981504);    // 524288
  short* wcWF  = (short*)(ws + 345505792);    // 524288
  float* hebb  = (float*)(ws + 346030080);    // 1048576
  float* f2sum = (float*)(ws + 347078656);    // 2048
  float* sacc  = (float*)(ws + 347080704);    // 256
  float* metab = (float*)(ws + 347080960);    // 262144
  float* sensb = (float*)(ws + 347343104);    // 262144
  float* gateb = (float*)(ws + 347605248);    // 262144
  float* part  = (float*)(ws + 347867392);    // 196608
  short* slowb = (short*)(ws + 0);            // overlay on outf (dead after CMS)
  short* fastb = (short*)(ws + 67108864);     // overlay on outf 2nd half

  float* o_ln = (float*)d_out;
  float* o_wf = o_ln + (size_t)NB*DD;
  float* o_st = o_wf + 262144;

  hipMemsetAsync(hebb, 0, 1048576, stream);
  hipMemsetAsync(f2sum, 0, 2048, stream);

  // weight casts to bf16
  k_castw<<<dim3((1572864+255)/256),256,0,stream>>>(w1, wcW1, 1572864);
  k_castw<<<dim3((1572864+255)/256),256,0,stream>>>(w2, wcW2, 1572864);
  k_castw<<<dim3((524288+255)/256),256,0,stream>>>(gmw, wcG, 524288);
  k_castw<<<dim3((524288+255)/256),256,0,stream>>>(gsw, wcG + 524288, 524288);
  k_castw<<<dim3((524288+255)/256),256,0,stream>>>(ggw, wcG + 1048576, 524288);
  k_castw<<<dim3((262144+255)/256),256,0,stream>>>(wslow, wcWS, 262144);
  k_castw<<<dim3((262144+255)/256),256,0,stream>>>(wfast, wcWF, 262144);
  k_castx<<<dim3(32768),256,0,stream>>>(x, outf, outb);

  const int freqs[3] = {1,4,16};
  for (int lv=0; lv<3; ++lv){
    k_gemm_h  <<<dim3(512,8),256,0,stream>>>(gs, freqs[lv], outb, wcW1 + (size_t)lv*524288, b1 + lv*HH, hbuf);
    k_gemm_res<<<dim3(512,4),256,0,stream>>>(gs, freqs[lv], hbuf, wcW2 + (size_t)lv*524288, b2 + lv*DD, outf, outb);
  }

  k_gates    <<<dim3(512,8),256,0,stream>>>(outb, wcG, gmb, gsb, ggb, hbuf);
  k_gateout  <<<dim3(16384),256,0,stream>>>(hbuf, gow, gob, metab, sensb, gateb, part);
  k_statreduce<<<dim3(1),256,0,stream>>>(part, sacc);
  k_slowfast <<<dim3(512,4),256,0,stream>>>(outb, wcWS, wcWF, slowb, fastb, f2sum);
  k_hebb     <<<dim3(4,4,64),256,0,stream>>>(fastb, outb, hebb);
  k_ln       <<<dim3(16384),256,0,stream>>>(slowb, fastb, gateb, sensb, gam, bet, o_ln);
  k_wfast    <<<dim3(1024),256,0,stream>>>(hebb, f2sum, sacc, wfast, o_wf, o_st);
}

// Round 2
// 2179.970 us; speedup vs baseline: 1.0766x; 1.0766x over previous
//
#include <hip/hip_runtime.h>
#include <hip/hip_bf16.h>
#include <cstdint>
#include <cstddef>

#define NB 65536
#define DD 512
#define HH 1024

typedef __attribute__((ext_vector_type(8))) short short8;
typedef __attribute__((ext_vector_type(4))) short short4v;
typedef __attribute__((ext_vector_type(4))) float f32x4;

__device__ __forceinline__ float bf2f(short s){
  union { float f; unsigned u; } v; v.u = ((unsigned)(unsigned short)s) << 16; return v.f;
}
__device__ __forceinline__ short f2bf(float f){
  union { float f; unsigned u; } v; v.f = f;
  unsigned u = v.u;
  u += 0x7FFFu + ((u >> 16) & 1u);
  return (short)(u >> 16);
}
__device__ __forceinline__ float sigm(float x){ return 1.0f / (1.0f + __expf(-x)); }

// ---- stage a 128x32 bf16 tile (rows row0..+128, cols k0..+32 of a row-major
// [rows][ldk] matrix) into linear LDS [128][32] via global_load_lds width 16.
__device__ __forceinline__ void stage128x32(const short* __restrict__ g, int row0, int ldk, int k0,
                                            short* lds_base, int wave, int lane){
#pragma unroll
  for (int i = 0; i < 2; ++i){
    int c = wave*2 + i;   // chunk 0..7, each = 16 rows = 1024B
    const short* src = g + (size_t)(row0 + c*16 + (lane>>2)) * (size_t)ldk
                         + (size_t)(k0 + (lane&3)*8);
    __builtin_amdgcn_global_load_lds((const __attribute__((address_space(1))) void*)src,
                                     (__attribute__((address_space(3))) void*)(lds_base + c*512),
                                     16, 0, 0);
  }
}

// ---- 128x128 tile NT GEMM core, 2-phase double-buffered (T3 recipe):
// prologue stage, then per K-step: {issue next-tile stage || ds_read cur || MFMA},
// single vmcnt(0)+barrier per step.
// C[m,n] = sum_k A[m,k]*W[n,k], A:MxK, W:NxK (both bf16 row-major)
// smem: 16384 shorts = 32 KB (2 bufs x (A 4096 + W 4096))
template<int K>
__device__ __forceinline__ void gemm_loop(const short* __restrict__ A, const short* __restrict__ W,
        int m0, int n0, short* smem, f32x4 acc[4][4], int wave, int lane)
{
  const int wm = (wave>>1)*64, wn = (wave&1)*64;
  const int lr = lane & 15, lk = (lane>>4)*8;
  // prologue: stage tile 0 into buf 0
  stage128x32(A, m0, K, 0, smem,        wave, lane);
  stage128x32(W, n0, K, 0, smem + 4096, wave, lane);
  asm volatile("s_waitcnt vmcnt(0)" ::: "memory");
  __builtin_amdgcn_s_barrier();
  int cur = 0;
  for (int k0 = 0; k0 < K; k0 += 32){
    short* buf  = smem + cur*8192;
    short* nbuf = smem + (cur^1)*8192;
    if (k0 + 32 < K){                       // issue NEXT tile's loads first
      stage128x32(A, m0, K, k0+32, nbuf,        wave, lane);
      stage128x32(W, n0, K, k0+32, nbuf + 4096, wave, lane);
    }
    short8 af[4], bf[4];
#pragma unroll
    for (int i=0;i<4;++i) af[i] = *(const short8*)&buf[(wm + i*16 + lr)*32 + lk];
#pragma unroll
    for (int i=0;i<4;++i) bf[i] = *(const short8*)&buf[4096 + (wn + i*16 + lr)*32 + lk];
    __builtin_amdgcn_s_setprio(1);
#pragma unroll
    for (int mi=0;mi<4;++mi)
#pragma unroll
      for (int ni=0;ni<4;++ni)
        acc[mi][ni] = __builtin_amdgcn_mfma_f32_16x16x32_bf16(af[mi], bf[ni], acc[mi][ni], 0, 0, 0);
    __builtin_amdgcn_s_setprio(0);
    asm volatile("s_waitcnt vmcnt(0)" ::: "memory");  // next tile's LDS writes done
    __builtin_amdgcn_s_barrier();
    cur ^= 1;
  }
}

#define ZERO_ACC(acc) \
  _Pragma("unroll") for (int zi=0;zi<4;++zi) _Pragma("unroll") for (int zj=0;zj<4;++zj) \
    acc[zi][zj] = (f32x4){0.f,0.f,0.f,0.f};

// ---- CMS level GEMM1: H = relu(out @ w1^T + b1), bf16 out
__global__ __launch_bounds__(256) void k_gemm_h(const int* __restrict__ gs, int freq,
     const short* __restrict__ A, const short* __restrict__ W1, const float* __restrict__ b1,
     short* __restrict__ Hout)
{
  if (gs[0] % freq) return;
  __shared__ __align__(16) short smem[16384];
  const int tid = threadIdx.x, wave = tid>>6, lane = tid&63;
  const int m0 = blockIdx.x*128, n0 = blockIdx.y*128;
  f32x4 acc[4][4]; ZERO_ACC(acc);
  gemm_loop<DD>(A, W1, m0, n0, smem, acc, wave, lane);
  const int wm=(wave>>1)*64, wn=(wave&1)*64;
  const int rbase = m0 + wm + ((lane>>4)<<2);
  const int cbase = n0 + wn + (lane&15);
#pragma unroll
  for (int ni=0;ni<4;++ni){
    const float bias = b1[cbase + ni*16];
#pragma unroll
    for (int mi=0;mi<4;++mi)
#pragma unroll
      for (int r=0;r<4;++r){
        float v = acc[mi][ni][r] + bias;
        v = v > 0.f ? v : 0.f;
        Hout[(size_t)(rbase + mi*16 + r)*HH + (cbase + ni*16)] = f2bf(v);
      }
  }
}

// ---- CMS level GEMM2: out += H @ w2^T + b2 (fp32 master + bf16 shadow)
__global__ __launch_bounds__(256) void k_gemm_res(const int* __restrict__ gs, int freq,
     const short* __restrict__ Hb, const short* __restrict__ W2, const float* __restrict__ b2,
     float* __restrict__ outf, short* __restrict__ outb)
{
  if (gs[0] % freq) return;
  __shared__ __align__(16) short smem[16384];
  const int tid = threadIdx.x, wave = tid>>6, lane = tid&63;
  const int m0 = blockIdx.x*128, n0 = blockIdx.y*128;
  f32x4 acc[4][4]; ZERO_ACC(acc);
  gemm_loop<HH>(Hb, W2, m0, n0, smem, acc, wave, lane);
  const int wm=(wave>>1)*64, wn=(wave&1)*64;
  const int rbase = m0 + wm + ((lane>>4)<<2);
  const int cbase = n0 + wn + (lane&15);
#pragma unroll
  for (int ni=0;ni<4;++ni){
    const float bias = b2[cbase + ni*16];
#pragma unroll
    for (int mi=0;mi<4;++mi)
#pragma unroll
      for (int r=0;r<4;++r){
        size_t off = (size_t)(rbase + mi*16 + r)*DD + (cbase + ni*16);
        float v = acc[mi][ni][r] + bias + outf[off];
        outf[off] = v;
        outb[off] = f2bf(v);
      }
  }
}

// ---- gates: gsum = sum_j sigmoid(x_cms @ gw_j^T + gb_j), bf16 out
__global__ __launch_bounds__(256) void k_gates(const short* __restrict__ A, const short* __restrict__ WG,
     const float* __restrict__ bm, const float* __restrict__ bs, const float* __restrict__ bg,
     short* __restrict__ GS)
{
  __shared__ __align__(16) short smem[16384];
  const int tid = threadIdx.x, wave = tid>>6, lane = tid&63;
  const int m0 = blockIdx.x*128, n0 = blockIdx.y*128;
  const int wm=(wave>>1)*64, wn=(wave&1)*64;
  const int rbase = m0 + wm + ((lane>>4)<<2);
  const int cbase = n0 + wn + (lane&15);
  f32x4 sum[4][4]; ZERO_ACC(sum);
  for (int j=0;j<3;++j){
    f32x4 acc[4][4]; ZERO_ACC(acc);
    gemm_loop<DD>(A, WG + (size_t)j*HH*DD, m0, n0, smem, acc, wave, lane);
    const float* bj = (j==0) ? bm : ((j==1) ? bs : bg);
#pragma unroll
    for (int ni=0;ni<4;++ni){
      const float bias = bj[cbase + ni*16];
#pragma unroll
      for (int mi=0;mi<4;++mi)
#pragma unroll
        for (int r=0;r<4;++r)
          sum[mi][ni][r] += sigm(acc[mi][ni][r] + bias);
    }
  }
#pragma unroll
  for (int ni=0;ni<4;++ni)
#pragma unroll
    for (int mi=0;mi<4;++mi)
#pragma unroll
      for (int r=0;r<4;++r)
        GS[(size_t)(rbase + mi*16 + r)*HH + (cbase + ni*16)] = f2bf(sum[mi][ni][r]);
}

// ---- slow/fast fused GEMM (shared A, two W), 2-phase double-buffered;
// also per-column sum of fast^2.  smem: 2 bufs x 3 tiles = 24576 shorts = 48 KB
__global__ __launch_bounds__(256) void k_slowfast(const short* __restrict__ A,
     const short* __restrict__ WS, const short* __restrict__ WF,
     short* __restrict__ SB, short* __restrict__ FB, float* __restrict__ f2sum)
{
  __shared__ __align__(16) short smem[24576];
  __shared__ float f2red[128];
  const int tid = threadIdx.x, wave = tid>>6, lane = tid&63;
  const int m0 = blockIdx.x*128, n0 = blockIdx.y*128;
  const int wm=(wave>>1)*64, wn=(wave&1)*64;
  const int lr = lane & 15, lk = (lane>>4)*8;
  f32x4 accS[4][4]; ZERO_ACC(accS);
  f32x4 accF[4][4]; ZERO_ACC(accF);
  stage128x32(A,  m0, DD, 0, smem,        wave, lane);
  stage128x32(WS, n0, DD, 0, smem + 4096, wave, lane);
  stage128x32(WF, n0, DD, 0, smem + 8192, wave, lane);
  asm volatile("s_waitcnt vmcnt(0)" ::: "memory");
  __builtin_amdgcn_s_barrier();
  int cur = 0;
  for (int k0 = 0; k0 < DD; k0 += 32){
    short* buf  = smem + cur*12288;
    short* nbuf = smem + (cur^1)*12288;
    if (k0 + 32 < DD){
      stage128x32(A,  m0, DD, k0+32, nbuf,        wave, lane);
      stage128x32(WS, n0, DD, k0+32, nbuf + 4096, wave, lane);
      stage128x32(WF, n0, DD, k0+32, nbuf + 8192, wave, lane);
    }
    short8 af[4], bsf[4], bff[4];
#pragma unroll
    for (int i=0;i<4;++i) af[i]  = *(const short8*)&buf[(wm + i*16 + lr)*32 + lk];
#pragma unroll
    for (int i=0;i<4;++i) bsf[i] = *(const short8*)&buf[4096 + (wn + i*16 + lr)*32 + lk];
#pragma unroll
    for (int i=0;i<4;++i) bff[i] = *(const short8*)&buf[8192 + (wn + i*16 + lr)*32 + lk];
    __builtin_amdgcn_s_setprio(1);
#pragma unroll
    for (int mi=0;mi<4;++mi)
#pragma unroll
      for (int ni=0;ni<4;++ni){
        accS[mi][ni] = __builtin_amdgcn_mfma_f32_16x16x32_bf16(af[mi], bsf[ni], accS[mi][ni], 0,0,0);
        accF[mi][ni] = __builtin_amdgcn_mfma_f32_16x16x32_bf16(af[mi], bff[ni], accF[mi][ni], 0,0,0);
      }
    __builtin_amdgcn_s_setprio(0);
    asm volatile("s_waitcnt vmcnt(0)" ::: "memory");
    __builtin_amdgcn_s_barrier();
    cur ^= 1;
  }
  for (int i=tid;i<128;i+=256) f2red[i]=0.f;
  __syncthreads();
  const int rbase = m0 + wm + ((lane>>4)<<2);
  const int ccol0 = wn + (lane&15);
#pragma unroll
  for (int ni=0;ni<4;++ni){
    const int ccol = ccol0 + ni*16;
    float p = 0.f;
#pragma unroll
    for (int mi=0;mi<4;++mi)
#pragma unroll
      for (int r=0;r<4;++r){
        float sv = accS[mi][ni][r], fv = accF[mi][ni][r];
        size_t off = (size_t)(rbase + mi*16 + r)*DD + (n0 + ccol);
        SB[off] = f2bf(sv);
        FB[off] = f2bf(fv);
        p += fv*fv;
      }
    atomicAdd(&f2red[ccol], p);
  }
  __syncthreads();
  if (tid < 128) atomicAdd(&f2sum[n0 + tid], f2red[tid]);
}

// ---- hebb = fast^T @ x_cms (TN GEMM via LDS transpose, split-K over B, atomic accum)
__global__ __launch_bounds__(256) void k_hebb(const short* __restrict__ FB,
     const short* __restrict__ XB, float* __restrict__ hebb)
{
  __shared__ __align__(16) short sT[10240];  // AsT[128][40] + BsT[128][40]
  const int tid = threadIdx.x, wave = tid>>6, lane = tid&63;
  const int o0 = blockIdx.x*128, d0 = blockIdx.y*128;
  const int bz = blockIdx.z;
  const int tr = tid>>3;          // 0..31 (b row in tile)
  const int tc = (tid&7)*16;      // col base
  const int wm=(wave>>1)*64, wn=(wave&1)*64;
  const int lr = lane & 15, lk = (lane>>4)*8;
  f32x4 acc[4][4]; ZERO_ACC(acc);
  for (int bb=0; bb<1024; bb+=32){
    const int b0 = bz*1024 + bb;
    __syncthreads();
#pragma unroll
    for (int h=0; h<2; ++h){
      short8 v = *(const short8*)&FB[(size_t)(b0+tr)*DD + o0 + tc + h*8];
#pragma unroll
      for (int j=0;j<8;++j) sT[(tc+h*8+j)*40 + tr] = v[j];
      short8 u = *(const short8*)&XB[(size_t)(b0+tr)*DD + d0 + tc + h*8];
#pragma unroll
      for (int j=0;j<8;++j) sT[5120 + (tc+h*8+j)*40 + tr] = u[j];
    }
    __syncthreads();
    short8 af[4], bf[4];
#pragma unroll
    for (int i=0;i<4;++i) af[i] = *(const short8*)&sT[(wm + i*16 + lr)*40 + lk];
#pragma unroll
    for (int i=0;i<4;++i) bf[i] = *(const short8*)&sT[5120 + (wn + i*16 + lr)*40 + lk];
#pragma unroll
    for (int mi=0;mi<4;++mi)
#pragma unroll
      for (int ni=0;ni<4;++ni)
        acc[mi][ni] = __builtin_amdgcn_mfma_f32_16x16x32_bf16(af[mi], bf[ni], acc[mi][ni], 0,0,0);
  }
  const int rbase = o0 + wm + ((lane>>4)<<2);
  const int cbase = d0 + wn + (lane&15);
#pragma unroll
  for (int mi=0;mi<4;++mi)
#pragma unroll
    for (int ni=0;ni<4;++ni)
#pragma unroll
      for (int r=0;r<4;++r)
        atomicAdd(&hebb[(size_t)(rbase + mi*16 + r)*DD + (cbase + ni*16)], acc[mi][ni][r]);
}

// ---- gate-out: gates = sigmoid(gsum @ g_out_w^T + g_out_b); per-block stat partials
__global__ __launch_bounds__(256) void k_gateout(const short* __restrict__ GS,
     const float* __restrict__ gow, const float* __restrict__ gob,
     float* __restrict__ metab, float* __restrict__ sens, float* __restrict__ gate,
     float* __restrict__ part)
{
  __shared__ float wsh[3072];
  __shared__ float red[12];
  const int tid = threadIdx.x, wave = tid>>6, lane = tid&63;
  for (int i=tid;i<3072;i+=256) wsh[i] = gow[i];
  __syncthreads();
  const int row = blockIdx.x*4 + wave;
  const int c0 = lane*16;
  short8 a = *(const short8*)&GS[(size_t)row*HH + c0];
  short8 b = *(const short8*)&GS[(size_t)row*HH + c0 + 8];
  float p0=0.f, p1=0.f, p2=0.f;
#pragma unroll
  for (int j=0;j<8;++j){ float v=bf2f(a[j]); int c=c0+j;   p0+=v*wsh[c]; p1+=v*wsh[1024+c]; p2+=v*wsh[2048+c]; }
#pragma unroll
  for (int j=0;j<8;++j){ float v=bf2f(b[j]); int c=c0+8+j; p0+=v*wsh[c]; p1+=v*wsh[1024+c]; p2+=v*wsh[2048+c]; }
  for (int off=32; off; off>>=1){
    p0 += __shfl_down(p0, off);
    p1 += __shfl_down(p1, off);
    p2 += __shfl_down(p2, off);
  }
  if (lane == 0){
    float m = sigm(p0 + gob[0]);
    float s = sigm(p1 + gob[1]);
    float g = sigm(p2 + gob[2]);
    metab[row]=m; sens[row]=s; gate[row]=g;
    red[wave*3+0]=m; red[wave*3+1]=s; red[wave*3+2]=g;
  }
  __syncthreads();
  if (tid < 3)
    part[(size_t)blockIdx.x*3 + tid] = red[tid] + red[3+tid] + red[6+tid] + red[9+tid];
}

__global__ __launch_bounds__(256) void k_statreduce(const float* __restrict__ part, float* __restrict__ sacc)
{
  __shared__ float sh[3][256];
  const int tid = threadIdx.x;
  float s0=0.f, s1=0.f, s2=0.f;
  for (int i=tid; i<16384; i+=256){ s0+=part[i*3]; s1+=part[i*3+1]; s2+=part[i*3+2]; }
  sh[0][tid]=s0; sh[1][tid]=s1; sh[2][tid]=s2;
  __syncthreads();
  if (tid < 3){
    float t=0.f;
    for (int i=0;i<256;++i) t += sh[tid][i];
    sacc[tid]=t;
  }
}

// ---- combined/SiLU-beta/LayerNorm epilogue: one wave per row
__global__ __launch_bounds__(256) void k_ln(const short* __restrict__ SB, const short* __restrict__ FB,
     const float* __restrict__ gate, const float* __restrict__ sens,
     const float* __restrict__ gam, const float* __restrict__ bet, float* __restrict__ out)
{
  const int tid = threadIdx.x, wave = tid>>6, lane = tid&63;
  const int row = blockIdx.x*4 + wave;
  const float g = gate[row], s = sens[row];
  const float bcoef = 0.5f + 2.0f*s;
  const int c0 = lane*8;
  short8 sv = *(const short8*)&SB[(size_t)row*DD + c0];
  short8 fv = *(const short8*)&FB[(size_t)row*DD + c0];
  float a[8]; float sum = 0.f;
#pragma unroll
  for (int j=0;j<8;++j){
    float c = bf2f(sv[j]) + bf2f(fv[j])*g;
    float av = c * sigm(bcoef*c);
    a[j] = av; sum += av;
  }
  for (int off=32; off; off>>=1) sum += __shfl_down(sum, off);
  sum = __shfl(sum, 0);
  const float mu = sum * (1.f/512.f);
  float vs = 0.f;
#pragma unroll
  for (int j=0;j<8;++j){ float d=a[j]-mu; vs += d*d; }
  for (int off=32; off; off>>=1) vs += __shfl_down(vs, off);
  vs = __shfl(vs, 0);
  const float rstd = rsqrtf(vs*(1.f/512.f) + 1e-5f);
  f32x4 o0, o1;
#pragma unroll
  for (int j=0;j<4;++j) o0[j] = (a[j]-mu)*rstd*gam[c0+j] + bet[c0+j];
#pragma unroll
  for (int j=0;j<4;++j) o1[j] = (a[4+j]-mu)*rstd*gam[c0+4+j] + bet[c0+4+j];
  *(f32x4*)&out[(size_t)row*DD + c0]     = o0;
  *(f32x4*)&out[(size_t)row*DD + c0 + 4] = o1;
}

// ---- new_W_fast + stats
__global__ __launch_bounds__(256) void k_wfast(const float* __restrict__ hebb,
     const float* __restrict__ f2sum, const float* __restrict__ sacc,
     const float* __restrict__ Wf, float* __restrict__ outw, float* __restrict__ outstats)
{
  const int idx = blockIdx.x*256 + threadIdx.x;
  if (idx >= 262144) return;
  const float inv = 1.f/65536.f;
  const float rate = sacc[0] * inv * 0.1f;
  const int o = idx >> 9;
  float w = Wf[idx];
  float h = hebb[idx] * inv;
  float forget = f2sum[o] * inv * w;
  outw[idx] = w + tanhf(h - forget) * rate;
  if (idx < 3) outstats[idx] = sacc[idx] * inv;
}

// ---- casts
__global__ __launch_bounds__(256) void k_castw(const float* __restrict__ src, short* __restrict__ dst, int n)
{
  int i = blockIdx.x*256 + threadIdx.x;
  if (i < n) dst[i] = f2bf(src[i]);
}
__global__ __launch_bounds__(256) void k_castx(const float* __restrict__ x,
     float* __restrict__ outf, short* __restrict__ outb)
{
  int i = blockIdx.x*256 + threadIdx.x;   // one float4 each; grid covers exactly
  f32x4 v = *(const f32x4*)&x[(size_t)i*4];
  *(f32x4*)&outf[(size_t)i*4] = v;
  short4v b;
#pragma unroll
  for (int j=0;j<4;++j) b[j] = f2bf(v[j]);
  *(short4v*)&outb[(size_t)i*4] = b;
}

extern "C" void kernel_launch(void* const* d_in, const int* in_sizes, int n_in,
                              void* d_out, int out_size, void* d_ws, size_t ws_size,
                              hipStream_t stream)
{
  const float* x    = (const float*)d_in[0];
  const int*   gs   = (const int*)d_in[1];
  const float* w1   = (const float*)d_in[2];
  const float* b1   = (const float*)d_in[3];
  const float* w2   = (const float*)d_in[4];
  const float* b2   = (const float*)d_in[5];
  const float* gmw  = (const float*)d_in[6];
  const float* gmb  = (const float*)d_in[7];
  const float* gsw  = (const float*)d_in[8];
  const float* gsb  = (const float*)d_in[9];
  const float* ggw  = (const float*)d_in[10];
  const float* ggb  = (const float*)d_in[11];
  const float* gow  = (const float*)d_in[12];
  const float* gob  = (const float*)d_in[13];
  const float* wslow= (const float*)d_in[14];
  const float* wfast= (const float*)d_in[15];
  const float* gam  = (const float*)d_in[16];
  const float* bet  = (const float*)d_in[17];

  char* ws = (char*)d_ws;
  float* outf  = (float*)(ws + 0);            // 134217728 B (dead after CMS -> reused below)
  short* outb  = (short*)(ws + 134217728);    // 67108864 B (x_cms bf16)
  short* hbuf  = (short*)(ws + 201326592);    // 134217728 B (h bf16, reused as gsum)
  short* wcW1  = (short*)(ws + 335544320);    // 3145728
  short* wcW2  = (short*)(ws + 338690048);    // 3145728
  short* wcG   = (short*)(ws + 341835776);    // 3145728
  short* wcWS  = (short*)(ws + 344981504);    // 524288
  short* wcWF  = (short*)(ws + 345505792);    // 524288
  float* hebb  = (float*)(ws + 346030080);    // 1048576
  float* f2sum = (float*)(ws + 347078656);    // 2048
  float* sacc  = (float*)(ws + 347080704);    // 256
  float* metab = (float*)(ws + 347080960);    // 262144
  float* sensb = (float*)(ws + 347343104);    // 262144
  float* gateb = (float*)(ws + 347605248);    // 262144
  float* part  = (float*)(ws + 347867392);    // 196608
  short* slowb = (short*)(ws + 0);            // overlay on outf (dead after CMS)
  short* fastb = (short*)(ws + 67108864);     // overlay on outf 2nd half

  float* o_ln = (float*)d_out;
  float* o_wf = o_ln + (size_t)NB*DD;
  float* o_st = o_wf + 262144;

  hipMemsetAsync(hebb, 0, 1048576, stream);
  hipMemsetAsync(f2sum, 0, 2048, stream);

  // weight casts to bf16
  k_castw<<<dim3((1572864+255)/256),256,0,stream>>>(w1, wcW1, 1572864);
  k_castw<<<dim3((1572864+255)/256),256,0,stream>>>(w2, wcW2, 1572864);
  k_castw<<<dim3((524288+255)/256),256,0,stream>>>(gmw, wcG, 524288);
  k_castw<<<dim3((524288+255)/256),256,0,stream>>>(gsw, wcG + 524288, 524288);
  k_castw<<<dim3((524288+255)/256),256,0,stream>>>(ggw, wcG + 1048576, 524288);
  k_castw<<<dim3((262144+255)/256),256,0,stream>>>(wslow, wcWS, 262144);
  k_castw<<<dim3((262144+255)/256),256,0,stream>>>(wfast, wcWF, 262144);
  k_castx<<<dim3(32768),256,0,stream>>>(x, outf, outb);

  const int freqs[3] = {1,4,16};
  for (int lv=0; lv<3; ++lv){
    k_gemm_h  <<<dim3(512,8),256,0,stream>>>(gs, freqs[lv], outb, wcW1 + (size_t)lv*524288, b1 + lv*HH, hbuf);
    k_gemm_res<<<dim3(512,4),256,0,stream>>>(gs, freqs[lv], hbuf, wcW2 + (size_t)lv*524288, b2 + lv*DD, outf, outb);
  }

  k_gates    <<<dim3(512,8),256,0,stream>>>(outb, wcG, gmb, gsb, ggb, hbuf);
  k_gateout  <<<dim3(16384),256,0,stream>>>(hbuf, gow, gob, metab, sensb, gateb, part);
  k_statreduce<<<dim3(1),256,0,stream>>>(part, sacc);
  k_slowfast <<<dim3(512,4),256,0,stream>>>(outb, wcWS, wcWF, slowb, fastb, f2sum);
  k_hebb     <<<dim3(4,4,64),256,0,stream>>>(fastb, outb, hebb);
  k_ln       <<<dim3(16384),256,0,stream>>>(slowb, fastb, gateb, sensb, gam, bet, o_ln);
  k_wfast    <<<dim3(1024),256,0,stream>>>(hebb, f2sum, sacc, wfast, o_wf, o_st);
}

// Round 3
// 2165.695 us; speedup vs baseline: 1.0837x; 1.0066x over previous
//
#include <hip/hip_runtime.h>
#include <hip/hip_bf16.h>
#include <cstdint>
#include <cstddef>

#define NB 65536
#define DD 512
#define HH 1024

typedef __attribute__((ext_vector_type(8))) short short8;
typedef __attribute__((ext_vector_type(4))) short short4v;
typedef __attribute__((ext_vector_type(4))) float f32x4;

__device__ __forceinline__ float bf2f(short s){
  union { float f; unsigned u; } v; v.u = ((unsigned)(unsigned short)s) << 16; return v.f;
}
__device__ __forceinline__ short f2bf(float f){
  union { float f; unsigned u; } v; v.f = f;
  unsigned u = v.u;
  u += 0x7FFFu + ((u >> 16) & 1u);
  return (short)(u >> 16);
}
__device__ __forceinline__ float sigm(float x){ return 1.0f / (1.0f + __expf(-x)); }

// sum over the 16 lanes of a DPP row (lanes lq*16..lq*16+15); result in all lanes
__device__ __forceinline__ float rowsum16(float v){
  int x;
  x = __builtin_amdgcn_update_dpp(0, __float_as_int(v), 0x128, 0xF, 0xF, true); v += __int_as_float(x); // ror:8
  x = __builtin_amdgcn_update_dpp(0, __float_as_int(v), 0x124, 0xF, 0xF, true); v += __int_as_float(x); // ror:4
  x = __builtin_amdgcn_update_dpp(0, __float_as_int(v), 0x122, 0xF, 0xF, true); v += __int_as_float(x); // ror:2
  x = __builtin_amdgcn_update_dpp(0, __float_as_int(v), 0x121, 0xF, 0xF, true); v += __int_as_float(x); // ror:1
  return v;
}

#define GLL(srcp, dstp) \
  __builtin_amdgcn_global_load_lds((const __attribute__((address_space(1))) void*)(srcp), \
                                   (__attribute__((address_space(3))) void*)(dstp), 16, 0, 0)

// ============================================================================
// 256x256-tile NT GEMM core, 8-phase-class schedule (T2+T3+T4+T5).
// C[m,n] = sum_k A[m,k]*W[n,k], A:[M][K], W:[N][K] bf16 row-major.
// 512 threads = 8 waves (2M x 4N), per-wave 128x64 output, acc[8][4].
// LDS 128 KiB: A: 2buf x [256 rows][64 cols] XOR-swizzled 16B granules;
//              B: 2buf x [2 khalf][128 superrow(=2 n-rows)][64] swizzled.
// Per K-tile 4 phases (s,a): (0,0),(0,1),(1,0),(1,1); each 16 MFMA.
// Stage schedule (steady): j0: A-a1(kt+1); j1: B-h1(kt+1); j2: B-h0(kt+2);
//                          j3: A-a0(kt+2).  vmcnt(8) at j0/j1/j3, none at j2.
// ============================================================================
template<int KTOT>
__device__ __forceinline__ void gemm256(const short* __restrict__ A, const short* __restrict__ W,
        int m0, int n0, short* smem, f32x4 acc[8][4])
{
  constexpr int NK = KTOT/64;
  static_assert(NK >= 4 && (NK & 1) == 0, "NK");
  const int tid = threadIdx.x;
  const int wave = tid>>6, lane = tid&63;
  const int wm = wave>>2, wn = wave&3;
  const int lr = lane&15, lq = lane>>4;

  // ---- ds_read bases (shorts)
  const int wmbase = wm*128 + lr;
  const int gA0 = (lq)     ^ (wmbase&7);
  const int gA1 = (4 + lq) ^ (wmbase&7);
  const int aBase0 = wmbase*64 + gA0*8;          // + p*16384 + (a*4+mi)*1024
  const int aBase1 = wmbase*64 + gA1*8;
  const int gB = ((lr&1)*4 + lq) ^ ((lr>>1)&7);
  const int bBase = 32768 + (wn*32 + (lr>>1))*64 + gB*8;  // + p*16384 + s*8192 + nf*512

  // ---- stage source addressing
  const int aRic = lane>>3;                      // row in 8-row chunk
  const int aCg  = (lane&7) ^ (aRic&7);          // logical col granule
  const int bSric = lane>>3;                     // superrow in chunk
  const int bG    = (lane&7) ^ (bSric&7);        // logical cc granule
  const int bN    = 2*bSric + (bG>>2);           // n offset within chunk
  const int bK    = (bG&3)*8;                    // k offset within half

  const short* aSrc = A + (size_t)(m0 + aRic)*KTOT + aCg*8;
  const short* bSrc = W + (size_t)(n0 + bN)*KTOT + bK;

#define STAGEA(kt2, a) { \
  const int p2_ = ((kt2)&1)*16384; \
  _Pragma("unroll") for (int i_=0;i_<2;++i_){ \
    int ci_ = wave*2 + i_; \
    int c_  = (a)*8 + ci_ + (ci_>=8 ? 8 : 0); \
    GLL(aSrc + (size_t)c_*8*KTOT + (kt2)*64, smem + p2_ + c_*512); } }

#define STAGEB(kt2, h) { \
  const int p2_ = ((kt2)&1)*16384; \
  _Pragma("unroll") for (int i_=0;i_<2;++i_){ \
    int ci_ = wave*2 + i_; \
    GLL(bSrc + (size_t)ci_*16*KTOT + (kt2)*64 + (h)*32, smem + 32768 + p2_ + (h)*8192 + ci_*512); } }

#define LOADA(pb, a, s) { \
  const int ab_ = (s) ? aBase1 : aBase0; \
  _Pragma("unroll") for (int mi_=0;mi_<4;++mi_) \
    af[mi_] = *(const short8*)&smem[(pb) + ab_ + ((a)*4+mi_)*1024]; }

#define LOADB(pb, s) { \
  _Pragma("unroll") for (int nf_=0;nf_<4;++nf_) \
    bf[nf_] = *(const short8*)&smem[(pb) + bBase + (s)*8192 + nf_*512]; }

#define MFMA16(a) { \
  __builtin_amdgcn_s_setprio(1); \
  _Pragma("unroll") for (int mi_=0;mi_<4;++mi_) \
  _Pragma("unroll") for (int nf_=0;nf_<4;++nf_) \
    acc[(a)*4+mi_][nf_] = __builtin_amdgcn_mfma_f32_16x16x32_bf16(af[mi_], bf[nf_], acc[(a)*4+mi_][nf_], 0,0,0); \
  __builtin_amdgcn_s_setprio(0); }

#define BAR1() { __builtin_amdgcn_s_barrier(); \
  asm volatile("s_waitcnt lgkmcnt(0)" ::: "memory"); \
  __builtin_amdgcn_sched_barrier(0); }

#define VM8()  asm volatile("s_waitcnt vmcnt(8)" ::: "memory")
#define BAR2() __builtin_amdgcn_s_barrier()
#define FENCE() asm volatile("" ::: "memory")

  short8 af[4], bf[4];

  // prologue: Bh0(0), Aa0(0), Aa1(0), Bh1(0), Bh0(1), Aa0(1)
  STAGEB(0,0); STAGEA(0,0); STAGEA(0,1); STAGEB(0,1); STAGEB(1,0); STAGEA(1,0);
  VM8(); BAR2();

#pragma unroll 2
  for (int kt = 0; kt < NK-2; ++kt){
    const int pb = (kt&1)*16384;
    // j0 (s=0,a=0)
    LOADA(pb,0,0); LOADB(pb,0); STAGEA(kt+1,1);
    BAR1(); MFMA16(0); VM8(); BAR2();
    // j1 (s=0,a=1)
    LOADA(pb,1,0); STAGEB(kt+1,1);
    BAR1(); MFMA16(1); VM8(); BAR2();
    // j2 (s=1,a=0)
    LOADA(pb,0,1); LOADB(pb,1); STAGEB(kt+2,0);
    BAR1(); MFMA16(0); FENCE(); BAR2();
    // j3 (s=1,a=1)
    LOADA(pb,1,1); STAGEA(kt+2,0);
    BAR1(); MFMA16(1); VM8(); BAR2();
  }
  { // peeled kt = NK-2
    const int kt = NK-2; const int pb = (kt&1)*16384;
    LOADA(pb,0,0); LOADB(pb,0); STAGEA(kt+1,1);
    BAR1(); MFMA16(0); VM8(); BAR2();
    LOADA(pb,1,0); STAGEB(kt+1,1);
    BAR1(); MFMA16(1); VM8(); BAR2();
    LOADA(pb,0,1); LOADB(pb,1);
    BAR1(); MFMA16(0); FENCE(); BAR2();
    LOADA(pb,1,1);
    BAR1(); MFMA16(1); asm volatile("s_waitcnt vmcnt(4)" ::: "memory"); BAR2();
  }
  { // peeled kt = NK-1
    const int pb = ((NK-1)&1)*16384;
    LOADA(pb,0,0); LOADB(pb,0);
    BAR1(); MFMA16(0); asm volatile("s_waitcnt vmcnt(2)" ::: "memory"); BAR2();
    LOADA(pb,1,0);
    BAR1(); MFMA16(1); asm volatile("s_waitcnt vmcnt(0)" ::: "memory"); BAR2();
    LOADA(pb,0,1); LOADB(pb,1);
    BAR1(); MFMA16(0); FENCE(); BAR2();
    LOADA(pb,1,1);
    BAR1(); MFMA16(1); FENCE(); BAR2();   // trailing barrier protects re-entry
  }
#undef STAGEA
#undef STAGEB
#undef LOADA
#undef LOADB
#undef MFMA16
#undef BAR1
#undef VM8
#undef BAR2
#undef FENCE
}

#define ZERO_ACC8(acc) \
  _Pragma("unroll") for (int zi=0;zi<8;++zi) _Pragma("unroll") for (int zj=0;zj<4;++zj) \
    acc[zi][zj] = (f32x4){0.f,0.f,0.f,0.f};

#define XCD_BX() ((blockIdx.x & 7)*32 + (blockIdx.x >> 3))

// ---- CMS level GEMM1: H = relu(out @ w1^T + b1), bf16 out. N=1024, K=512
__global__ __launch_bounds__(512, 2) void k_gemm_h(const int* __restrict__ gs, int freq,
     const short* __restrict__ A, const short* __restrict__ W1, const float* __restrict__ b1,
     short* __restrict__ Hout)
{
  if (gs[0] % freq) return;
  __shared__ __align__(16) short smem[65536];
  const int tid = threadIdx.x, wave = tid>>6, lane = tid&63;
  const int wm = wave>>2, wn = wave&3, lr = lane&15, lq = lane>>4;
  const int m0 = XCD_BX()*256, n0 = blockIdx.y*256;
  f32x4 acc[8][4]; ZERO_ACC8(acc);
  gemm256<DD>(A, W1, m0, n0, smem, acc);
  const int rb = m0 + wm*128 + lq*4;
  const int cb = n0 + wn*64 + lr;
#pragma unroll
  for (int nf=0;nf<4;++nf){
    const float bias = b1[cb + nf*16];
#pragma unroll
    for (int mf=0;mf<8;++mf)
#pragma unroll
      for (int rr=0;rr<4;++rr){
        float v = acc[mf][nf][rr] + bias;
        v = v > 0.f ? v : 0.f;
        Hout[(size_t)(rb + mf*16 + rr)*HH + (cb + nf*16)] = f2bf(v);
      }
  }
}

// ---- CMS level GEMM2: out += H @ w2^T + b2 (fp32 master + bf16 shadow). N=512, K=1024
__global__ __launch_bounds__(512, 2) void k_gemm_res(const int* __restrict__ gs, int freq,
     const short* __restrict__ Hb, const short* __restrict__ W2, const float* __restrict__ b2,
     float* __restrict__ outf, short* __restrict__ outb)
{
  if (gs[0] % freq) return;
  __shared__ __align__(16) short smem[65536];
  const int tid = threadIdx.x, wave = tid>>6, lane = tid&63;
  const int wm = wave>>2, wn = wave&3, lr = lane&15, lq = lane>>4;
  const int m0 = XCD_BX()*256, n0 = blockIdx.y*256;
  f32x4 acc[8][4]; ZERO_ACC8(acc);
  gemm256<HH>(Hb, W2, m0, n0, smem, acc);
  const int rb = m0 + wm*128 + lq*4;
  const int cb = n0 + wn*64 + lr;
#pragma unroll
  for (int nf=0;nf<4;++nf){
    const float bias = b2[cb + nf*16];
#pragma unroll
    for (int mf=0;mf<8;++mf)
#pragma unroll
      for (int rr=0;rr<4;++rr){
        size_t off = (size_t)(rb + mf*16 + rr)*DD + (cb + nf*16);
        float v = acc[mf][nf][rr] + bias + outf[off];
        outf[off] = v;
        outb[off] = f2bf(v);
      }
  }
}

// ---- gates fused with gate-out: for each j, sigmoid(x@gwj^T+bj), dotted with
// the 3 g_out_w rows, row-reduced, atomically accumulated into pacc[row][3].
__global__ __launch_bounds__(512, 2) void k_gates(const short* __restrict__ A, const short* __restrict__ WG,
     const float* __restrict__ bm, const float* __restrict__ bs, const float* __restrict__ bg,
     const float* __restrict__ gow, float* __restrict__ pacc)
{
  __shared__ __align__(16) short smem[65536];
  const int tid = threadIdx.x, wave = tid>>6, lane = tid&63;
  const int wm = wave>>2, wn = wave&3, lr = lane&15, lq = lane>>4;
  const int m0 = XCD_BX()*256, n0 = blockIdx.y*256;
  const int rb = m0 + wm*128 + lq*4;
  const int cb = n0 + wn*64 + lr;
  float gw0[4], gw1[4], gw2[4];
#pragma unroll
  for (int nf=0;nf<4;++nf){
    gw0[nf] = gow[cb + nf*16];
    gw1[nf] = gow[1024 + cb + nf*16];
    gw2[nf] = gow[2048 + cb + nf*16];
  }
#pragma unroll 1
  for (int j=0;j<3;++j){
    const float* bj = (j==0) ? bm : ((j==1) ? bs : bg);
    float bias[4];
#pragma unroll
    for (int nf=0;nf<4;++nf) bias[nf] = bj[cb + nf*16];
    f32x4 acc[8][4]; ZERO_ACC8(acc);
    gemm256<DD>(A, WG + (size_t)j*HH*DD, m0, n0, smem, acc);
#pragma unroll
    for (int mf=0;mf<8;++mf)
#pragma unroll
      for (int rr=0;rr<4;++rr){
        float s0=0.f, s1=0.f, s2=0.f;
#pragma unroll
        for (int nf=0;nf<4;++nf){
          float v = sigm(acc[mf][nf][rr] + bias[nf]);
          s0 += v*gw0[nf]; s1 += v*gw1[nf]; s2 += v*gw2[nf];
        }
        s0 = rowsum16(s0); s1 = rowsum16(s1); s2 = rowsum16(s2);
        if (lr == 0){
          int row = rb + mf*16 + rr;
          atomicAdd(&pacc[(size_t)row*3+0], s0);
          atomicAdd(&pacc[(size_t)row*3+1], s1);
          atomicAdd(&pacc[(size_t)row*3+2], s2);
        }
      }
  }
}

// ---- slow/fast as one N=1024 GEMM (W = [W_slow; W_fast] contiguous), K=512
__global__ __launch_bounds__(512, 2) void k_slowfast(const short* __restrict__ A,
     const short* __restrict__ WSF,
     short* __restrict__ SB, short* __restrict__ FB, float* __restrict__ f2sum)
{
  __shared__ __align__(16) short smem[65536];
  __shared__ float f2red[256];
  const int tid = threadIdx.x, wave = tid>>6, lane = tid&63;
  const int wm = wave>>2, wn = wave&3, lr = lane&15, lq = lane>>4;
  const int m0 = XCD_BX()*256, n0 = blockIdx.y*256;
  const bool isfast = (n0 >= 512);
  if (isfast){
    for (int i=tid;i<256;i+=512) f2red[i]=0.f;
    __syncthreads();
  }
  f32x4 acc[8][4]; ZERO_ACC8(acc);
  gemm256<DD>(A, WSF, m0, n0, smem, acc);
  const int rb = m0 + wm*128 + lq*4;
  const int cb = n0 + wn*64 + lr;
  if (!isfast){
#pragma unroll
    for (int nf=0;nf<4;++nf)
#pragma unroll
      for (int mf=0;mf<8;++mf)
#pragma unroll
        for (int rr=0;rr<4;++rr)
          SB[(size_t)(rb + mf*16 + rr)*DD + (cb + nf*16)] = f2bf(acc[mf][nf][rr]);
  } else {
#pragma unroll
    for (int nf=0;nf<4;++nf){
      float p = 0.f;
      const int fcol = cb + nf*16 - 512;
#pragma unroll
      for (int mf=0;mf<8;++mf)
#pragma unroll
        for (int rr=0;rr<4;++rr){
          float fv = acc[mf][nf][rr];
          FB[(size_t)(rb + mf*16 + rr)*DD + fcol] = f2bf(fv);
          p += fv*fv;
        }
      atomicAdd(&f2red[wn*64 + nf*16 + lr], p);
    }
    __syncthreads();
    if (tid < 256) atomicAdd(&f2sum[(n0-512) + tid], f2red[tid]);
  }
}

// ---- hebb = fast^T @ x_cms (TN GEMM via LDS transpose, split-K over B, atomic accum)
__global__ __launch_bounds__(256) void k_hebb(const short* __restrict__ FB,
     const short* __restrict__ XB, float* __restrict__ hebb)
{
  __shared__ __align__(16) short sT[10240];
  const int tid = threadIdx.x, wave = tid>>6, lane = tid&63;
  const int o0 = blockIdx.x*128, d0 = blockIdx.y*128;
  const int bz = blockIdx.z;
  const int tr = tid>>3;
  const int tc = (tid&7)*16;
  const int wm=(wave>>1)*64, wn=(wave&1)*64;
  const int lr = lane & 15, lk = (lane>>4)*8;
  f32x4 acc[4][4];
#pragma unroll
  for (int zi=0;zi<4;++zi)
#pragma unroll
    for (int zj=0;zj<4;++zj) acc[zi][zj] = (f32x4){0.f,0.f,0.f,0.f};
  for (int bb=0; bb<1024; bb+=32){
    const int b0 = bz*1024 + bb;
    __syncthreads();
#pragma unroll
    for (int h=0; h<2; ++h){
      short8 v = *(const short8*)&FB[(size_t)(b0+tr)*DD + o0 + tc + h*8];
#pragma unroll
      for (int j=0;j<8;++j) sT[(tc+h*8+j)*40 + tr] = v[j];
      short8 u = *(const short8*)&XB[(size_t)(b0+tr)*DD + d0 + tc + h*8];
#pragma unroll
      for (int j=0;j<8;++j) sT[5120 + (tc+h*8+j)*40 + tr] = u[j];
    }
    __syncthreads();
    short8 af[4], bf[4];
#pragma unroll
    for (int i=0;i<4;++i) af[i] = *(const short8*)&sT[(wm + i*16 + lr)*40 + lk];
#pragma unroll
    for (int i=0;i<4;++i) bf[i] = *(const short8*)&sT[5120 + (wn + i*16 + lr)*40 + lk];
#pragma unroll
    for (int mi=0;mi<4;++mi)
#pragma unroll
      for (int ni=0;ni<4;++ni)
        acc[mi][ni] = __builtin_amdgcn_mfma_f32_16x16x32_bf16(af[mi], bf[ni], acc[mi][ni], 0,0,0);
  }
  const int rbase = o0 + wm + ((lane>>4)<<2);
  const int cbase = d0 + wn + (lane&15);
#pragma unroll
  for (int mi=0;mi<4;++mi)
#pragma unroll
    for (int ni=0;ni<4;++ni)
#pragma unroll
      for (int r=0;r<4;++r)
        atomicAdd(&hebb[(size_t)(rbase + mi*16 + r)*DD + (cbase + ni*16)], acc[mi][ni][r]);
}

// ---- finalize gates: sigmoid(pacc + gob) -> sens/gate arrays + stat sums
__global__ __launch_bounds__(256) void k_gatefin(const float* __restrict__ pacc,
     const float* __restrict__ gob,
     float* __restrict__ sensb, float* __restrict__ gateb, float* __restrict__ sacc)
{
  __shared__ float red[3][256];
  const int tid = threadIdx.x;
  const int row = blockIdx.x*256 + tid;
  float m = sigm(pacc[(size_t)row*3+0] + gob[0]);
  float s = sigm(pacc[(size_t)row*3+1] + gob[1]);
  float g = sigm(pacc[(size_t)row*3+2] + gob[2]);
  sensb[row] = s; gateb[row] = g;
  red[0][tid]=m; red[1][tid]=s; red[2][tid]=g;
  __syncthreads();
  for (int off=128; off; off>>=1){
    if (tid < off){
      red[0][tid]+=red[0][tid+off];
      red[1][tid]+=red[1][tid+off];
      red[2][tid]+=red[2][tid+off];
    }
    __syncthreads();
  }
  if (tid < 3) atomicAdd(&sacc[tid], red[tid][0]);
}

// ---- combined/SiLU-beta/LayerNorm epilogue: one wave per row
__global__ __launch_bounds__(256) void k_ln(const short* __restrict__ SB, const short* __restrict__ FB,
     const float* __restrict__ gate, const float* __restrict__ sens,
     const float* __restrict__ gam, const float* __restrict__ bet, float* __restrict__ out)
{
  const int tid = threadIdx.x, wave = tid>>6, lane = tid&63;
  const int row = blockIdx.x*4 + wave;
  const float g = gate[row], s = sens[row];
  const float bcoef = 0.5f + 2.0f*s;
  const int c0 = lane*8;
  short8 sv = *(const short8*)&SB[(size_t)row*DD + c0];
  short8 fv = *(const short8*)&FB[(size_t)row*DD + c0];
  float a[8]; float sum = 0.f;
#pragma unroll
  for (int j=0;j<8;++j){
    float c = bf2f(sv[j]) + bf2f(fv[j])*g;
    float av = c * sigm(bcoef*c);
    a[j] = av; sum += av;
  }
  for (int off=32; off; off>>=1) sum += __shfl_down(sum, off);
  sum = __shfl(sum, 0);
  const float mu = sum * (1.f/512.f);
  float vs = 0.f;
#pragma unroll
  for (int j=0;j<8;++j){ float d=a[j]-mu; vs += d*d; }
  for (int off=32; off; off>>=1) vs += __shfl_down(vs, off);
  vs = __shfl(vs, 0);
  const float rstd = rsqrtf(vs*(1.f/512.f) + 1e-5f);
  f32x4 o0, o1;
#pragma unroll
  for (int j=0;j<4;++j) o0[j] = (a[j]-mu)*rstd*gam[c0+j] + bet[c0+j];
#pragma unroll
  for (int j=0;j<4;++j) o1[j] = (a[4+j]-mu)*rstd*gam[c0+4+j] + bet[c0+4+j];
  *(f32x4*)&out[(size_t)row*DD + c0]     = o0;
  *(f32x4*)&out[(size_t)row*DD + c0 + 4] = o1;
}

// ---- new_W_fast + stats
__global__ __launch_bounds__(256) void k_wfast(const float* __restrict__ hebb,
     const float* __restrict__ f2sum, const float* __restrict__ sacc,
     const float* __restrict__ Wf, float* __restrict__ outw, float* __restrict__ outstats)
{
  const int idx = blockIdx.x*256 + threadIdx.x;
  if (idx >= 262144) return;
  const float inv = 1.f/65536.f;
  const float rate = sacc[0] * inv * 0.1f;
  const int o = idx >> 9;
  float w = Wf[idx];
  float h = hebb[idx] * inv;
  float forget = f2sum[o] * inv * w;
  outw[idx] = w + tanhf(h - forget) * rate;
  if (idx < 3) outstats[idx] = sacc[idx] * inv;
}

// ---- casts
__global__ __launch_bounds__(256) void k_castw(const float* __restrict__ src, short* __restrict__ dst, int n)
{
  int i = blockIdx.x*256 + threadIdx.x;
  if (i < n) dst[i] = f2bf(src[i]);
}
__global__ __launch_bounds__(256) void k_castx(const float* __restrict__ x,
     float* __restrict__ outf, short* __restrict__ outb)
{
  int i = blockIdx.x*256 + threadIdx.x;
  f32x4 v = *(const f32x4*)&x[(size_t)i*4];
  *(f32x4*)&outf[(size_t)i*4] = v;
  short4v b;
#pragma unroll
  for (int j=0;j<4;++j) b[j] = f2bf(v[j]);
  *(short4v*)&outb[(size_t)i*4] = b;
}

extern "C" void kernel_launch(void* const* d_in, const int* in_sizes, int n_in,
                              void* d_out, int out_size, void* d_ws, size_t ws_size,
                              hipStream_t stream)
{
  const float* x    = (const float*)d_in[0];
  const int*   gs   = (const int*)d_in[1];
  const float* w1   = (const float*)d_in[2];
  const float* b1   = (const float*)d_in[3];
  const float* w2   = (const float*)d_in[4];
  const float* b2   = (const float*)d_in[5];
  const float* gmw  = (const float*)d_in[6];
  const float* gmb  = (const float*)d_in[7];
  const float* gsw  = (const float*)d_in[8];
  const float* gsb  = (const float*)d_in[9];
  const float* ggw  = (const float*)d_in[10];
  const float* ggb  = (const float*)d_in[11];
  const float* gow  = (const float*)d_in[12];
  const float* gob  = (const float*)d_in[13];
  const float* wslow= (const float*)d_in[14];
  const float* wfast= (const float*)d_in[15];
  const float* gam  = (const float*)d_in[16];
  const float* bet  = (const float*)d_in[17];

  char* ws = (char*)d_ws;
  float* outf  = (float*)(ws + 0);            // fp32 x_cms master (dead after CMS)
  short* outb  = (short*)(ws + 134217728);    // x_cms bf16
  short* hbuf  = (short*)(ws + 201326592);    // H bf16 (CMS); pacc overlays later
  short* wcW1  = (short*)(ws + 335544320);
  short* wcW2  = (short*)(ws + 338690048);
  short* wcG   = (short*)(ws + 341835776);
  short* wcWSF = (short*)(ws + 344981504);    // [W_slow;W_fast] = [1024][512] bf16
  float* hebb  = (float*)(ws + 346030080);
  float* f2sum = (float*)(ws + 347078656);
  float* sacc  = (float*)(ws + 347080704);
  float* sensb = (float*)(ws + 347080960);
  float* gateb = (float*)(ws + 347343104);
  float* pacc  = (float*)(ws + 201326592);    // overlays hbuf (dead after CMS)
  short* slowb = (short*)(ws + 0);            // overlays outf (dead after CMS)
  short* fastb = (short*)(ws + 67108864);

  float* o_ln = (float*)d_out;
  float* o_wf = o_ln + (size_t)NB*DD;
  float* o_st = o_wf + 262144;

  hipMemsetAsync(hebb, 0, 1048576, stream);
  hipMemsetAsync(f2sum, 0, 2048, stream);

  k_castw<<<dim3(6144),256,0,stream>>>(w1, wcW1, 1572864);
  k_castw<<<dim3(6144),256,0,stream>>>(w2, wcW2, 1572864);
  k_castw<<<dim3(2048),256,0,stream>>>(gmw, wcG, 524288);
  k_castw<<<dim3(2048),256,0,stream>>>(gsw, wcG + 524288, 524288);
  k_castw<<<dim3(2048),256,0,stream>>>(ggw, wcG + 1048576, 524288);
  k_castw<<<dim3(1024),256,0,stream>>>(wslow, wcWSF, 262144);
  k_castw<<<dim3(1024),256,0,stream>>>(wfast, wcWSF + 262144, 262144);
  k_castx<<<dim3(32768),256,0,stream>>>(x, outf, outb);

  const int freqs[3] = {1,4,16};
  for (int lv=0; lv<3; ++lv){
    k_gemm_h  <<<dim3(256,4),512,0,stream>>>(gs, freqs[lv], outb, wcW1 + (size_t)lv*524288, b1 + lv*HH, hbuf);
    k_gemm_res<<<dim3(256,2),512,0,stream>>>(gs, freqs[lv], hbuf, wcW2 + (size_t)lv*524288, b2 + lv*DD, outf, outb);
  }

  // hbuf dead from here; overlay pacc
  hipMemsetAsync(pacc, 0, 786432, stream);
  hipMemsetAsync(sacc, 0, 256, stream);

  k_gates   <<<dim3(256,4),512,0,stream>>>(outb, wcG, gmb, gsb, ggb, gow, pacc);
  k_gatefin <<<dim3(256),256,0,stream>>>(pacc, gob, sensb, gateb, sacc);
  k_slowfast<<<dim3(256,4),512,0,stream>>>(outb, wcWSF, slowb, fastb, f2sum);
  k_hebb    <<<dim3(4,4,64),256,0,stream>>>(fastb, outb, hebb);
  k_ln      <<<dim3(16384),256,0,stream>>>(slowb, fastb, gateb, sensb, gam, bet, o_ln);
  k_wfast   <<<dim3(1024),256,0,stream>>>(hebb, f2sum, sacc, wfast, o_wf, o_st);
}

// Round 4
// 1736.898 us; speedup vs baseline: 1.3512x; 1.2469x over previous
//
#include <hip/hip_runtime.h>
#include <hip/hip_bf16.h>
#include <cstdint>
#include <cstddef>

#define NB 65536
#define DD 512
#define HH 1024

typedef __attribute__((ext_vector_type(8))) short short8;
typedef __attribute__((ext_vector_type(4))) short short4v;
typedef __attribute__((ext_vector_type(4))) float f32x4;

__device__ __forceinline__ float bf2f(short s){
  union { float f; unsigned u; } v; v.u = ((unsigned)(unsigned short)s) << 16; return v.f;
}
__device__ __forceinline__ short f2bf(float f){
  union { float f; unsigned u; } v; v.f = f;
  unsigned u = v.u;
  u += 0x7FFFu + ((u >> 16) & 1u);
  return (short)(u >> 16);
}
__device__ __forceinline__ float sigm(float x){ return 1.0f / (1.0f + __expf(-x)); }

// sum over the 16 lanes of a DPP row (lanes lq*16..lq*16+15); result in all lanes
__device__ __forceinline__ float rowsum16(float v){
  int x;
  x = __builtin_amdgcn_update_dpp(0, __float_as_int(v), 0x128, 0xF, 0xF, true); v += __int_as_float(x); // ror:8
  x = __builtin_amdgcn_update_dpp(0, __float_as_int(v), 0x124, 0xF, 0xF, true); v += __int_as_float(x); // ror:4
  x = __builtin_amdgcn_update_dpp(0, __float_as_int(v), 0x122, 0xF, 0xF, true); v += __int_as_float(x); // ror:2
  x = __builtin_amdgcn_update_dpp(0, __float_as_int(v), 0x121, 0xF, 0xF, true); v += __int_as_float(x); // ror:1
  return v;
}

// XCD-bijective remap: each XCD gets a contiguous m-range; the NX (n/j)-blocks
// sharing one A-tile run consecutively on the same XCD -> A-tile L2 reuse.
__device__ __forceinline__ int2 xcd_remap(int NX, int G){
  int flat = blockIdx.y*NX + blockIdx.x;
  int l = (flat & 7)*(G>>3) + (flat>>3);
  return make_int2(l / NX, l % NX);   // (m-tile, xj)
}

#define GLL(srcp, dstp) \
  __builtin_amdgcn_global_load_lds((const __attribute__((address_space(1))) void*)(srcp), \
                                   (__attribute__((address_space(3))) void*)(dstp), 16, 0, 0)

// ============================================================================
// 256x256-tile NT GEMM core, 8-phase-class schedule (T2+T3+T4+T5).
// C[m,n] = sum_k A[m,k]*W[n,k], A:[M][K], W:[N][K] bf16 row-major.
// 512 threads = 8 waves (2M x 4N), per-wave 128x64 output, acc[8][4].
// LDS 128 KiB: A: 2buf x [256 rows][64 cols] XOR-swizzled 16B granules;
//              B: 2buf x [2 khalf][128 superrow(=2 n-rows)][64] swizzled.
// Per K-tile 4 phases (s,a); each 16 MFMA; counted vmcnt(8), never 0 in loop.
// ============================================================================
template<int KTOT>
__device__ __forceinline__ void gemm256(const short* __restrict__ A, const short* __restrict__ W,
        int m0, int n0, short* smem, f32x4 acc[8][4])
{
  constexpr int NK = KTOT/64;
  static_assert(NK >= 4 && (NK & 1) == 0, "NK");
  const int tid = threadIdx.x;
  const int wave = tid>>6, lane = tid&63;
  const int wm = wave>>2, wn = wave&3;
  const int lr = lane&15, lq = lane>>4;

  // ---- ds_read bases (shorts)
  const int wmbase = wm*128 + lr;
  const int gA0 = (lq)     ^ (wmbase&7);
  const int gA1 = (4 + lq) ^ (wmbase&7);
  const int aBase0 = wmbase*64 + gA0*8;          // + p*16384 + (a*4+mi)*1024
  const int aBase1 = wmbase*64 + gA1*8;
  const int gB = ((lr&1)*4 + lq) ^ ((lr>>1)&7);
  const int bBase = 32768 + (wn*32 + (lr>>1))*64 + gB*8;  // + p*16384 + s*8192 + nf*512

  // ---- stage source addressing
  const int aRic = lane>>3;                      // row in 8-row chunk
  const int aCg  = (lane&7) ^ (aRic&7);          // logical col granule
  const int bSric = lane>>3;                     // superrow in chunk
  const int bG    = (lane&7) ^ (bSric&7);        // logical cc granule
  const int bN    = 2*bSric + (bG>>2);           // n offset within chunk
  const int bK    = (bG&3)*8;                    // k offset within half

  const short* aSrc = A + (size_t)(m0 + aRic)*KTOT + aCg*8;
  const short* bSrc = W + (size_t)(n0 + bN)*KTOT + bK;

#define STAGEA(kt2, a) { \
  const int p2_ = ((kt2)&1)*16384; \
  _Pragma("unroll") for (int i_=0;i_<2;++i_){ \
    int ci_ = wave*2 + i_; \
    int c_  = (a)*8 + ci_ + (ci_>=8 ? 8 : 0); \
    GLL(aSrc + (size_t)c_*8*KTOT + (kt2)*64, smem + p2_ + c_*512); } }

#define STAGEB(kt2, h) { \
  const int p2_ = ((kt2)&1)*16384; \
  _Pragma("unroll") for (int i_=0;i_<2;++i_){ \
    int ci_ = wave*2 + i_; \
    GLL(bSrc + (size_t)ci_*16*KTOT + (kt2)*64 + (h)*32, smem + 32768 + p2_ + (h)*8192 + ci_*512); } }

#define LOADA(pb, a, s) { \
  const int ab_ = (s) ? aBase1 : aBase0; \
  _Pragma("unroll") for (int mi_=0;mi_<4;++mi_) \
    af[mi_] = *(const short8*)&smem[(pb) + ab_ + ((a)*4+mi_)*1024]; }

#define LOADB(pb, s) { \
  _Pragma("unroll") for (int nf_=0;nf_<4;++nf_) \
    bf[nf_] = *(const short8*)&smem[(pb) + bBase + (s)*8192 + nf_*512]; }

#define MFMA16(a) { \
  __builtin_amdgcn_s_setprio(1); \
  _Pragma("unroll") for (int mi_=0;mi_<4;++mi_) \
  _Pragma("unroll") for (int nf_=0;nf_<4;++nf_) \
    acc[(a)*4+mi_][nf_] = __builtin_amdgcn_mfma_f32_16x16x32_bf16(af[mi_], bf[nf_], acc[(a)*4+mi_][nf_], 0,0,0); \
  __builtin_amdgcn_s_setprio(0); }

#define BAR1() { __builtin_amdgcn_s_barrier(); \
  asm volatile("s_waitcnt lgkmcnt(0)" ::: "memory"); \
  __builtin_amdgcn_sched_barrier(0); }

#define VM8()  asm volatile("s_waitcnt vmcnt(8)" ::: "memory")
#define BAR2() __builtin_amdgcn_s_barrier()
#define FENCE() asm volatile("" ::: "memory")

  short8 af[4], bf[4];

  // prologue: Bh0(0), Aa0(0), Aa1(0), Bh1(0), Bh0(1), Aa0(1)
  STAGEB(0,0); STAGEA(0,0); STAGEA(0,1); STAGEB(0,1); STAGEB(1,0); STAGEA(1,0);
  VM8(); BAR2();

#pragma unroll 2
  for (int kt = 0; kt < NK-2; ++kt){
    const int pb = (kt&1)*16384;
    // j0 (s=0,a=0)
    LOADA(pb,0,0); LOADB(pb,0); STAGEA(kt+1,1);
    BAR1(); MFMA16(0); VM8(); BAR2();
    // j1 (s=0,a=1)
    LOADA(pb,1,0); STAGEB(kt+1,1);
    BAR1(); MFMA16(1); VM8(); BAR2();
    // j2 (s=1,a=0)
    LOADA(pb,0,1); LOADB(pb,1); STAGEB(kt+2,0);
    BAR1(); MFMA16(0); FENCE(); BAR2();
    // j3 (s=1,a=1)
    LOADA(pb,1,1); STAGEA(kt+2,0);
    BAR1(); MFMA16(1); VM8(); BAR2();
  }
  { // peeled kt = NK-2
    const int kt = NK-2; const int pb = (kt&1)*16384;
    LOADA(pb,0,0); LOADB(pb,0); STAGEA(kt+1,1);
    BAR1(); MFMA16(0); VM8(); BAR2();
    LOADA(pb,1,0); STAGEB(kt+1,1);
    BAR1(); MFMA16(1); VM8(); BAR2();
    LOADA(pb,0,1); LOADB(pb,1);
    BAR1(); MFMA16(0); FENCE(); BAR2();
    LOADA(pb,1,1);
    BAR1(); MFMA16(1); asm volatile("s_waitcnt vmcnt(4)" ::: "memory"); BAR2();
  }
  { // peeled kt = NK-1
    const int pb = ((NK-1)&1)*16384;
    LOADA(pb,0,0); LOADB(pb,0);
    BAR1(); MFMA16(0); asm volatile("s_waitcnt vmcnt(2)" ::: "memory"); BAR2();
    LOADA(pb,1,0);
    BAR1(); MFMA16(1); asm volatile("s_waitcnt vmcnt(0)" ::: "memory"); BAR2();
    LOADA(pb,0,1); LOADB(pb,1);
    BAR1(); MFMA16(0); FENCE(); BAR2();
    LOADA(pb,1,1);
    BAR1(); MFMA16(1); FENCE(); BAR2();   // trailing barrier protects re-entry
  }
#undef STAGEA
#undef STAGEB
#undef LOADA
#undef LOADB
#undef MFMA16
#undef BAR1
#undef VM8
#undef BAR2
#undef FENCE
}

#define ZERO_ACC8(acc) \
  _Pragma("unroll") for (int zi=0;zi<8;++zi) _Pragma("unroll") for (int zj=0;zj<4;++zj) \
    acc[zi][zj] = (f32x4){0.f,0.f,0.f,0.f};

// ---- CMS level GEMM1: H = relu(out @ w1^T + b1), bf16 out. N=1024, K=512
__global__ __launch_bounds__(512, 2) void k_gemm_h(const int* __restrict__ gs, int freq,
     const short* __restrict__ A, const short* __restrict__ W1, const float* __restrict__ b1,
     short* __restrict__ Hout)
{
  if (gs[0] % freq) return;
  __shared__ __align__(16) short smem[65536];
  const int tid = threadIdx.x, wave = tid>>6, lane = tid&63;
  const int wm = wave>>2, wn = wave&3, lr = lane&15, lq = lane>>4;
  int2 r = xcd_remap(4, 1024);
  const int m0 = r.x*256, n0 = r.y*256;
  f32x4 acc[8][4]; ZERO_ACC8(acc);
  gemm256<DD>(A, W1, m0, n0, smem, acc);
  const int rb = m0 + wm*128 + lq*4;
  const int cb = n0 + wn*64 + lr;
#pragma unroll
  for (int nf=0;nf<4;++nf){
    const float bias = b1[cb + nf*16];
#pragma unroll
    for (int mf=0;mf<8;++mf)
#pragma unroll
      for (int rr=0;rr<4;++rr){
        float v = acc[mf][nf][rr] + bias;
        v = v > 0.f ? v : 0.f;
        Hout[(size_t)(rb + mf*16 + rr)*HH + (cb + nf*16)] = f2bf(v);
      }
  }
}

// ---- CMS level GEMM2: out += H @ w2^T + b2 (fp32 master + bf16 shadow). N=512, K=1024
__global__ __launch_bounds__(512, 2) void k_gemm_res(const int* __restrict__ gs, int freq,
     const short* __restrict__ Hb, const short* __restrict__ W2, const float* __restrict__ b2,
     float* __restrict__ outf, short* __restrict__ outb)
{
  if (gs[0] % freq) return;
  __shared__ __align__(16) short smem[65536];
  const int tid = threadIdx.x, wave = tid>>6, lane = tid&63;
  const int wm = wave>>2, wn = wave&3, lr = lane&15, lq = lane>>4;
  int2 r = xcd_remap(2, 512);
  const int m0 = r.x*256, n0 = r.y*256;
  f32x4 acc[8][4]; ZERO_ACC8(acc);
  gemm256<HH>(Hb, W2, m0, n0, smem, acc);
  const int rb = m0 + wm*128 + lq*4;
  const int cb = n0 + wn*64 + lr;
#pragma unroll
  for (int nf=0;nf<4;++nf){
    const float bias = b2[cb + nf*16];
#pragma unroll
    for (int mf=0;mf<8;++mf)
#pragma unroll
      for (int rr=0;rr<4;++rr){
        size_t off = (size_t)(rb + mf*16 + rr)*DD + (cb + nf*16);
        float v = acc[mf][nf][rr] + bias + outf[off];
        outf[off] = v;
        outb[off] = f2bf(v);
      }
  }
}

// ---- gates fused with gate-out: block handles one (j, n-tile); per-row dot
// with the 3 g_out_w rows, reduced in LDS, stored as NON-ATOMIC partials
// pacc[12][65536][3]; k_gatefin sums the 12 slices.
__global__ __launch_bounds__(512, 2) void k_gates(const short* __restrict__ A, const short* __restrict__ WG,
     const float* __restrict__ bm, const float* __restrict__ bs, const float* __restrict__ bg,
     const float* __restrict__ gow, float* __restrict__ pacc)
{
  __shared__ __align__(16) short smem[65536];
  __shared__ float sred[768];
  const int tid = threadIdx.x, wave = tid>>6, lane = tid&63;
  const int wm = wave>>2, wn = wave&3, lr = lane&15, lq = lane>>4;
  int2 r = xcd_remap(12, 3072);
  const int m0 = r.x*256, xj = r.y;
  const int j = xj >> 2, nb = xj & 3;
  const int n0 = nb*256;
  const int cb = n0 + wn*64 + lr;
  const float* bj = (j==0) ? bm : ((j==1) ? bs : bg);
  float gw0[4], gw1[4], gw2[4], bias[4];
#pragma unroll
  for (int nf=0;nf<4;++nf){
    gw0[nf]  = gow[cb + nf*16];
    gw1[nf]  = gow[1024 + cb + nf*16];
    gw2[nf]  = gow[2048 + cb + nf*16];
    bias[nf] = bj[cb + nf*16];
  }
  for (int i=tid;i<768;i+=512) sred[i]=0.f;
  f32x4 acc[8][4]; ZERO_ACC8(acc);
  gemm256<DD>(A, WG + (size_t)j*HH*DD, m0, n0, smem, acc);
  __syncthreads();
#pragma unroll
  for (int mf=0;mf<8;++mf)
#pragma unroll
    for (int rr=0;rr<4;++rr){
      float s0=0.f, s1=0.f, s2=0.f;
#pragma unroll
      for (int nf=0;nf<4;++nf){
        float v = sigm(acc[mf][nf][rr] + bias[nf]);
        s0 += v*gw0[nf]; s1 += v*gw1[nf]; s2 += v*gw2[nf];
      }
      s0 = rowsum16(s0); s1 = rowsum16(s1); s2 = rowsum16(s2);
      if (lr == 0){
        int lrow = wm*128 + mf*16 + lq*4 + rr;
        atomicAdd(&sred[lrow], s0);          // LDS-scope atomics (4 waves/row)
        atomicAdd(&sred[256+lrow], s1);
        atomicAdd(&sred[512+lrow], s2);
      }
    }
  __syncthreads();
  if (tid < 256){
    float* dst = &pacc[((size_t)xj*NB + m0 + tid)*3];
    dst[0] = sred[tid];
    dst[1] = sred[256+tid];
    dst[2] = sred[512+tid];
  }
}

// ---- slow/fast as one N=1024 GEMM (W = [W_slow; W_fast] contiguous), K=512
__global__ __launch_bounds__(512, 2) void k_slowfast(const short* __restrict__ A,
     const short* __restrict__ WSF,
     short* __restrict__ SB, short* __restrict__ FB, float* __restrict__ f2sum)
{
  __shared__ __align__(16) short smem[65536];
  __shared__ float f2red[256];
  const int tid = threadIdx.x, wave = tid>>6, lane = tid&63;
  const int wm = wave>>2, wn = wave&3, lr = lane&15, lq = lane>>4;
  int2 r = xcd_remap(4, 1024);
  const int m0 = r.x*256, n0 = r.y*256;
  const bool isfast = (n0 >= 512);
  if (isfast){
    for (int i=tid;i<256;i+=512) f2red[i]=0.f;
    __syncthreads();
  }
  f32x4 acc[8][4]; ZERO_ACC8(acc);
  gemm256<DD>(A, WSF, m0, n0, smem, acc);
  const int rb = m0 + wm*128 + lq*4;
  const int cb = n0 + wn*64 + lr;
  if (!isfast){
#pragma unroll
    for (int nf=0;nf<4;++nf)
#pragma unroll
      for (int mf=0;mf<8;++mf)
#pragma unroll
        for (int rr=0;rr<4;++rr)
          SB[(size_t)(rb + mf*16 + rr)*DD + (cb + nf*16)] = f2bf(acc[mf][nf][rr]);
  } else {
#pragma unroll
    for (int nf=0;nf<4;++nf){
      float p = 0.f;
      const int fcol = cb + nf*16 - 512;
#pragma unroll
      for (int mf=0;mf<8;++mf)
#pragma unroll
        for (int rr=0;rr<4;++rr){
          float fv = acc[mf][nf][rr];
          FB[(size_t)(rb + mf*16 + rr)*DD + fcol] = f2bf(fv);
          p += fv*fv;
        }
      atomicAdd(&f2red[wn*64 + nf*16 + lr], p);
    }
    __syncthreads();
    if (tid < 256) atomicAdd(&f2sum[(n0-512) + tid], f2red[tid]);
  }
}

// ---- hebb = fast^T @ x_cms (TN GEMM via LDS transpose, split-K=16 over B)
__global__ __launch_bounds__(256) void k_hebb(const short* __restrict__ FB,
     const short* __restrict__ XB, float* __restrict__ hebb)
{
  __shared__ __align__(16) short sT[10240];
  const int tid = threadIdx.x, wave = tid>>6, lane = tid&63;
  const int o0 = blockIdx.x*128, d0 = blockIdx.y*128;
  const int bz = blockIdx.z;
  const int tr = tid>>3;
  const int tc = (tid&7)*16;
  const int wm=(wave>>1)*64, wn=(wave&1)*64;
  const int lr = lane & 15, lk = (lane>>4)*8;
  f32x4 acc[4][4];
#pragma unroll
  for (int zi=0;zi<4;++zi)
#pragma unroll
    for (int zj=0;zj<4;++zj) acc[zi][zj] = (f32x4){0.f,0.f,0.f,0.f};
  for (int bb=0; bb<4096; bb+=32){
    const int b0 = bz*4096 + bb;
    __syncthreads();
#pragma unroll
    for (int h=0; h<2; ++h){
      short8 v = *(const short8*)&FB[(size_t)(b0+tr)*DD + o0 + tc + h*8];
#pragma unroll
      for (int j=0;j<8;++j) sT[(tc+h*8+j)*40 + tr] = v[j];
      short8 u = *(const short8*)&XB[(size_t)(b0+tr)*DD + d0 + tc + h*8];
#pragma unroll
      for (int j=0;j<8;++j) sT[5120 + (tc+h*8+j)*40 + tr] = u[j];
    }
    __syncthreads();
    short8 af[4], bf[4];
#pragma unroll
    for (int i=0;i<4;++i) af[i] = *(const short8*)&sT[(wm + i*16 + lr)*40 + lk];
#pragma unroll
    for (int i=0;i<4;++i) bf[i] = *(const short8*)&sT[5120 + (wn + i*16 + lr)*40 + lk];
#pragma unroll
    for (int mi=0;mi<4;++mi)
#pragma unroll
      for (int ni=0;ni<4;++ni)
        acc[mi][ni] = __builtin_amdgcn_mfma_f32_16x16x32_bf16(af[mi], bf[ni], acc[mi][ni], 0,0,0);
  }
  const int rbase = o0 + wm + ((lane>>4)<<2);
  const int cbase = d0 + wn + (lane&15);
#pragma unroll
  for (int mi=0;mi<4;++mi)
#pragma unroll
    for (int ni=0;ni<4;++ni)
#pragma unroll
      for (int r=0;r<4;++r)
        atomicAdd(&hebb[(size_t)(rbase + mi*16 + r)*DD + (cbase + ni*16)], acc[mi][ni][r]);
}

// ---- finalize gates: sum 12 partial slices, sigmoid, stats
__global__ __launch_bounds__(256) void k_gatefin(const float* __restrict__ pacc,
     const float* __restrict__ gob,
     float* __restrict__ sensb, float* __restrict__ gateb, float* __restrict__ sacc)
{
  __shared__ float red[3][256];
  const int tid = threadIdx.x;
  const int row = blockIdx.x*256 + tid;
  float a0=0.f, a1=0.f, a2=0.f;
#pragma unroll
  for (int sidx=0; sidx<12; ++sidx){
    const float* p = &pacc[((size_t)sidx*NB + row)*3];
    a0 += p[0]; a1 += p[1]; a2 += p[2];
  }
  float m = sigm(a0 + gob[0]);
  float s = sigm(a1 + gob[1]);
  float g = sigm(a2 + gob[2]);
  sensb[row] = s; gateb[row] = g;
  red[0][tid]=m; red[1][tid]=s; red[2][tid]=g;
  __syncthreads();
  for (int off=128; off; off>>=1){
    if (tid < off){
      red[0][tid]+=red[0][tid+off];
      red[1][tid]+=red[1][tid+off];
      red[2][tid]+=red[2][tid+off];
    }
    __syncthreads();
  }
  if (tid < 3) atomicAdd(&sacc[tid], red[tid][0]);
}

// ---- combined/SiLU-beta/LayerNorm epilogue: one wave per row
__global__ __launch_bounds__(256) void k_ln(const short* __restrict__ SB, const short* __restrict__ FB,
     const float* __restrict__ gate, const float* __restrict__ sens,
     const float* __restrict__ gam, const float* __restrict__ bet, float* __restrict__ out)
{
  const int tid = threadIdx.x, wave = tid>>6, lane = tid&63;
  const int row = blockIdx.x*4 + wave;
  const float g = gate[row], s = sens[row];
  const float bcoef = 0.5f + 2.0f*s;
  const int c0 = lane*8;
  short8 sv = *(const short8*)&SB[(size_t)row*DD + c0];
  short8 fv = *(const short8*)&FB[(size_t)row*DD + c0];
  float a[8]; float sum = 0.f;
#pragma unroll
  for (int j=0;j<8;++j){
    float c = bf2f(sv[j]) + bf2f(fv[j])*g;
    float av = c * sigm(bcoef*c);
    a[j] = av; sum += av;
  }
  for (int off=32; off; off>>=1) sum += __shfl_down(sum, off);
  sum = __shfl(sum, 0);
  const float mu = sum * (1.f/512.f);
  float vs = 0.f;
#pragma unroll
  for (int j=0;j<8;++j){ float d=a[j]-mu; vs += d*d; }
  for (int off=32; off; off>>=1) vs += __shfl_down(vs, off);
  vs = __shfl(vs, 0);
  const float rstd = rsqrtf(vs*(1.f/512.f) + 1e-5f);
  f32x4 o0, o1;
#pragma unroll
  for (int j=0;j<4;++j) o0[j] = (a[j]-mu)*rstd*gam[c0+j] + bet[c0+j];
#pragma unroll
  for (int j=0;j<4;++j) o1[j] = (a[4+j]-mu)*rstd*gam[c0+4+j] + bet[c0+4+j];
  *(f32x4*)&out[(size_t)row*DD + c0]     = o0;
  *(f32x4*)&out[(size_t)row*DD + c0 + 4] = o1;
}

// ---- new_W_fast + stats
__global__ __launch_bounds__(256) void k_wfast(const float* __restrict__ hebb,
     const float* __restrict__ f2sum, const float* __restrict__ sacc,
     const float* __restrict__ Wf, float* __restrict__ outw, float* __restrict__ outstats)
{
  const int idx = blockIdx.x*256 + threadIdx.x;
  if (idx >= 262144) return;
  const float inv = 1.f/65536.f;
  const float rate = sacc[0] * inv * 0.1f;
  const int o = idx >> 9;
  float w = Wf[idx];
  float h = hebb[idx] * inv;
  float forget = f2sum[o] * inv * w;
  outw[idx] = w + tanhf(h - forget) * rate;
  if (idx < 3) outstats[idx] = sacc[idx] * inv;
}

// ---- casts
__global__ __launch_bounds__(256) void k_castw(const float* __restrict__ src, short* __restrict__ dst, int n)
{
  int i = blockIdx.x*256 + threadIdx.x;
  if (i < n) dst[i] = f2bf(src[i]);
}
__global__ __launch_bounds__(256) void k_castx(const float* __restrict__ x,
     float* __restrict__ outf, short* __restrict__ outb)
{
  int i = blockIdx.x*256 + threadIdx.x;
  f32x4 v = *(const f32x4*)&x[(size_t)i*4];
  *(f32x4*)&outf[(size_t)i*4] = v;
  short4v b;
#pragma unroll
  for (int j=0;j<4;++j) b[j] = f2bf(v[j]);
  *(short4v*)&outb[(size_t)i*4] = b;
}

extern "C" void kernel_launch(void* const* d_in, const int* in_sizes, int n_in,
                              void* d_out, int out_size, void* d_ws, size_t ws_size,
                              hipStream_t stream)
{
  const float* x    = (const float*)d_in[0];
  const int*   gs   = (const int*)d_in[1];
  const float* w1   = (const float*)d_in[2];
  const float* b1   = (const float*)d_in[3];
  const float* w2   = (const float*)d_in[4];
  const float* b2   = (const float*)d_in[5];
  const float* gmw  = (const float*)d_in[6];
  const float* gmb  = (const float*)d_in[7];
  const float* gsw  = (const float*)d_in[8];
  const float* gsb  = (const float*)d_in[9];
  const float* ggw  = (const float*)d_in[10];
  const float* ggb  = (const float*)d_in[11];
  const float* gow  = (const float*)d_in[12];
  const float* gob  = (const float*)d_in[13];
  const float* wslow= (const float*)d_in[14];
  const float* wfast= (const float*)d_in[15];
  const float* gam  = (const float*)d_in[16];
  const float* bet  = (const float*)d_in[17];

  char* ws = (char*)d_ws;
  float* outf  = (float*)(ws + 0);            // fp32 x_cms master (dead after CMS)
  short* outb  = (short*)(ws + 134217728);    // x_cms bf16
  short* hbuf  = (short*)(ws + 201326592);    // H bf16 (CMS); pacc overlays later
  short* wcW1  = (short*)(ws + 335544320);
  short* wcW2  = (short*)(ws + 338690048);
  short* wcG   = (short*)(ws + 341835776);
  short* wcWSF = (short*)(ws + 344981504);    // [W_slow;W_fast] = [1024][512] bf16
  float* hebb  = (float*)(ws + 346030080);
  float* f2sum = (float*)(ws + 347078656);
  float* sacc  = (float*)(ws + 347080704);
  float* sensb = (float*)(ws + 347080960);
  float* gateb = (float*)(ws + 347343104);
  float* pacc  = (float*)(ws + 201326592);    // overlays hbuf (dead after CMS), 9.4 MB
  short* slowb = (short*)(ws + 0);            // overlays outf (dead after CMS)
  short* fastb = (short*)(ws + 67108864);

  float* o_ln = (float*)d_out;
  float* o_wf = o_ln + (size_t)NB*DD;
  float* o_st = o_wf + 262144;

  hipMemsetAsync(hebb, 0, 1048576, stream);
  hipMemsetAsync(f2sum, 0, 2048, stream);
  hipMemsetAsync(sacc, 0, 256, stream);

  k_castw<<<dim3(6144),256,0,stream>>>(w1, wcW1, 1572864);
  k_castw<<<dim3(6144),256,0,stream>>>(w2, wcW2, 1572864);
  k_castw<<<dim3(2048),256,0,stream>>>(gmw, wcG, 524288);
  k_castw<<<dim3(2048),256,0,stream>>>(gsw, wcG + 524288, 524288);
  k_castw<<<dim3(2048),256,0,stream>>>(ggw, wcG + 1048576, 524288);
  k_castw<<<dim3(1024),256,0,stream>>>(wslow, wcWSF, 262144);
  k_castw<<<dim3(1024),256,0,stream>>>(wfast, wcWSF + 262144, 262144);
  k_castx<<<dim3(32768),256,0,stream>>>(x, outf, outb);

  const int freqs[3] = {1,4,16};
  for (int lv=0; lv<3; ++lv){
    k_gemm_h  <<<dim3(4,256),512,0,stream>>>(gs, freqs[lv], outb, wcW1 + (size_t)lv*524288, b1 + lv*HH, hbuf);
    k_gemm_res<<<dim3(2,256),512,0,stream>>>(gs, freqs[lv], hbuf, wcW2 + (size_t)lv*524288, b2 + lv*DD, outf, outb);
  }

  k_gates   <<<dim3(12,256),512,0,stream>>>(outb, wcG, gmb, gsb, ggb, gow, pacc);
  k_gatefin <<<dim3(256),256,0,stream>>>(pacc, gob, sensb, gateb, sacc);
  k_slowfast<<<dim3(4,256),512,0,stream>>>(outb, wcWSF, slowb, fastb, f2sum);
  k_hebb    <<<dim3(4,4,16),256,0,stream>>>(fastb, outb, hebb);
  k_ln      <<<dim3(16384),256,0,stream>>>(slowb, fastb, gateb, sensb, gam, bet, o_ln);
  k_wfast   <<<dim3(1024),256,0,stream>>>(hebb, f2sum, sacc, wfast, o_wf, o_st);
}